// Round 4
// baseline (382.802 us; speedup 1.0000x reference)
//
#include <hip/hip_runtime.h>
#include <math.h>

#define EMBED 1024
#define HEADS 16
#define HD    64
#define NB    4
#define LSEQ  2048

typedef __attribute__((ext_vector_type(8))) short bf16x8;
typedef __attribute__((ext_vector_type(16))) float f32x16;

typedef __attribute__((address_space(1))) void as1_void;
typedef __attribute__((address_space(3))) void as3_void;

__device__ __forceinline__ void gload_lds16(const void* g, void* l) {
    __builtin_amdgcn_global_load_lds((const as1_void*)g, (as3_void*)l, 16, 0, 0);
}

__device__ inline bf16x8 as_bf16x8(uint4 u) {
    union { uint4 u; bf16x8 b; } c; c.u = u; return c.b;
}
// round-to-nearest-even fp32 -> bf16 (raw ushort); finite inputs only
__device__ inline unsigned short bf16r(float x) {
    unsigned u = __float_as_uint(x);
    u += 0x7fffu + ((u >> 16) & 1u);
    return (unsigned short)(u >> 16);
}
__device__ inline float bfh2f(unsigned short h) {
    return __uint_as_float(((unsigned)h) << 16);
}
// split two floats into packed hi/lo bf16 words
__device__ inline void split2(float x, float y, unsigned& hw, unsigned& lw) {
    unsigned short hx = bf16r(x), hy = bf16r(y);
    unsigned short lx = bf16r(x - bfh2f(hx)), ly = bf16r(y - bfh2f(hy));
    hw = (unsigned)hx | ((unsigned)hy << 16);
    lw = (unsigned)lx | ((unsigned)ly << 16);
}

// ---------------------------------------------------------------------------
// Kernel 1: QKV projections as split-bf16 MFMA GEMM (unchanged from R6).
// ---------------------------------------------------------------------------
__global__ __launch_bounds__(256, 3) void proj_kernel(
    const float* __restrict__ Xv, const float* __restrict__ Xk, const float* __restrict__ Xq,
    const float* __restrict__ Wv, const float* __restrict__ Wk, const float* __restrict__ Wq,
    unsigned short* __restrict__ Vt, unsigned short* __restrict__ Kp, unsigned short* __restrict__ Qp)
{
    __shared__ uint4 sXh[128 * 8];   // [token][granule of 8 dims]  16KB
    __shared__ uint4 sXl[128 * 8];   // 16KB
    __shared__ uint4 sWh[64 * 8];    // [e][granule of 8 dims]       8KB
    __shared__ uint4 sWl[64 * 8];    //                              8KB

    const int t = threadIdx.x;
    const int lane = t & 63, w = t >> 6;
    const int l5 = lane & 31, hi = lane >> 5;
    const int h  = blockIdx.y;
    const int n  = blockIdx.x >> 4;
    const int l0 = (blockIdx.x & 15) * 128;

    const float QSC = 1.44269504088896341f / 32.0f;
    const float* Xs[3] = {Xv, Xk, Xq};
    const float* Ws[3] = {Wv, Wk, Wq};

    const int frow = t >> 4;        // staging: row group 0..15
    const int fcol = t & 15;        // float4 index within 64-dim row

    for (int p = 0; p < 3; ++p) {
        __syncthreads();
        // ---- stage X tile: 128 rows x 64 dims fp32 -> hi/lo bf16, swizzled ----
        {
            const float* xb = Xs[p] + ((size_t)(n * LSEQ + l0 + frow)) * EMBED + h * HD + fcol * 4;
            unsigned short* dh = (unsigned short*)sXh;
            unsigned short* dl = (unsigned short*)sXl;
            #pragma unroll
            for (int i = 0; i < 8; ++i) {
                int row = frow + i * 16;
                float4 v = *(const float4*)(xb + (size_t)i * 16 * EMBED);
                int gg = fcol >> 1, s8 = (fcol & 1) * 4;
                int idx = row * 64 + ((gg ^ (row & 7)) * 8) + s8;
                uint2 hv, lv;
                split2(v.x, v.y, hv.x, lv.x);
                split2(v.z, v.w, hv.y, lv.y);
                *(uint2*)(dh + idx) = hv;
                *(uint2*)(dl + idx) = lv;
            }
        }
        // ---- stage W: 64x64 fp32 -> hi/lo bf16, swizzled ----
        #pragma unroll
        for (int i = 0; i < 2; ++i) {
            int u = t + 256 * i;                  // granule 0..511
            int e = u >> 3, g = u & 7;
            const float* wb = Ws[p] + u * 8;
            float4 v0 = *(const float4*)(wb);
            float4 v1 = *(const float4*)(wb + 4);
            uint4 hq, lq;
            split2(v0.x, v0.y, hq.x, lq.x);
            split2(v0.z, v0.w, hq.y, lq.y);
            split2(v1.x, v1.y, hq.z, lq.z);
            split2(v1.z, v1.w, hq.w, lq.w);
            int idx = e * 8 + (g ^ (e & 7));
            sWh[idx] = hq;
            sWl[idx] = lq;
        }
        __syncthreads();

        // ---- MFMA: per wave, 32-token tile x (two 32-wide e-tiles) ----
        f32x16 acc0, acc1;
        #pragma unroll
        for (int i = 0; i < 16; ++i) { acc0[i] = 0.f; acc1[i] = 0.f; }

        const int xrow = w * 32 + l5;
        const int w0r = l5, w1r = 32 + l5;
        #pragma unroll
        for (int kc = 0; kc < 4; ++kc) {
            int gsel = kc * 2 + hi;
            bf16x8 xh = as_bf16x8(sXh[xrow * 8 + (gsel ^ (xrow & 7))]);
            bf16x8 xl = as_bf16x8(sXl[xrow * 8 + (gsel ^ (xrow & 7))]);
            bf16x8 wh0 = as_bf16x8(sWh[w0r * 8 + (gsel ^ (w0r & 7))]);
            bf16x8 wl0 = as_bf16x8(sWl[w0r * 8 + (gsel ^ (w0r & 7))]);
            bf16x8 wh1 = as_bf16x8(sWh[w1r * 8 + (gsel ^ (w1r & 7))]);
            bf16x8 wl1 = as_bf16x8(sWl[w1r * 8 + (gsel ^ (w1r & 7))]);
            if (p == 0) {
                // V^T = W X^T : A=W-frag (rows e), B=X-frag (cols token)
                acc0 = __builtin_amdgcn_mfma_f32_32x32x16_bf16(wh0, xh, acc0, 0, 0, 0);
                acc0 = __builtin_amdgcn_mfma_f32_32x32x16_bf16(wh0, xl, acc0, 0, 0, 0);
                acc0 = __builtin_amdgcn_mfma_f32_32x32x16_bf16(wl0, xh, acc0, 0, 0, 0);
                acc1 = __builtin_amdgcn_mfma_f32_32x32x16_bf16(wh1, xh, acc1, 0, 0, 0);
                acc1 = __builtin_amdgcn_mfma_f32_32x32x16_bf16(wh1, xl, acc1, 0, 0, 0);
                acc1 = __builtin_amdgcn_mfma_f32_32x32x16_bf16(wl1, xh, acc1, 0, 0, 0);
            } else {
                // C = X W^T : A=X-frag (rows token), B=W-frag (cols e)
                acc0 = __builtin_amdgcn_mfma_f32_32x32x16_bf16(xh, wh0, acc0, 0, 0, 0);
                acc0 = __builtin_amdgcn_mfma_f32_32x32x16_bf16(xh, wl0, acc0, 0, 0, 0);
                acc0 = __builtin_amdgcn_mfma_f32_32x32x16_bf16(xl, wh0, acc0, 0, 0, 0);
                acc1 = __builtin_amdgcn_mfma_f32_32x32x16_bf16(xh, wh1, acc1, 0, 0, 0);
                acc1 = __builtin_amdgcn_mfma_f32_32x32x16_bf16(xh, wl1, acc1, 0, 0, 0);
                acc1 = __builtin_amdgcn_mfma_f32_32x32x16_bf16(xl, wh1, acc1, 0, 0, 0);
            }
        }

        // ---- epilogue ----
        if (p == 0) {
            // C rows = e, cols = token (V^T): coalesced Vt [N,H,D,L] stores
            unsigned short* vb = Vt + (((size_t)(n * HEADS + h)) * HD) * LSEQ + l0 + w * 32 + l5;
            #pragma unroll
            for (int r = 0; r < 16; ++r) {
                int er = (r & 3) + 8 * (r >> 2) + 4 * hi;
                vb[(size_t)er * LSEQ]        = bf16r(acc0[r]);
                vb[(size_t)(32 + er) * LSEQ] = bf16r(acc1[r]);
            }
        } else {
            unsigned short* dst = (p == 1) ? Kp : Qp;
            float sc = (p == 2) ? QSC : 1.0f;
            unsigned short* db = dst + (((size_t)(n * HEADS + h)) * LSEQ + l0 + w * 32) * HD;
            #pragma unroll
            for (int r = 0; r < 16; ++r) {
                int tok = (r & 3) + 8 * (r >> 2) + 4 * hi;
                db[(size_t)tok * HD + l5]      = bf16r(acc0[r] * sc);
                db[(size_t)tok * HD + 32 + l5] = bf16r(acc1[r] * sc);
            }
        }
    }
}

// ---------------------------------------------------------------------------
// Kernel 2: MFMA flash attention, S^T orientation.
// R9 change: deepen the LDS swizzle from ^(row&7) to ^((row^(row>>3))&7) on
// both K and V (read side AND the pre-swizzled global source in STAGE).
// With the old swizzle, rows r, r+8, r+16, r+24 within one ds_read_b128 got
// identical granule slots -> same 4 banks -> 4-way conflict on every K-frag
// and V-frag read (SQ_LDS_BANK_CONFLICT pinned at 8.39e6 ~ 13.6us/CU).
// With SW(row)=(row^(row>>3))&7 each 8-lane group covers all 32 banks
// exactly once -> uniform bank load (the b128 floor). The source permutation
// stays within each 128B row -> staging coalescing unchanged.  Everything
// else (double-buffer, counted vmcnt(4), setprio, in-reg P) as R8.
// ---------------------------------------------------------------------------
__global__ __launch_bounds__(256, 4) void attn_kernel(
    const unsigned short* __restrict__ Qp, const unsigned short* __restrict__ Kp,
    const unsigned short* __restrict__ Vt,
    unsigned short* __restrict__ AOh, unsigned short* __restrict__ AOl)
{
    __shared__ uint4 sK[2][64 * 8];  // [buf][key][granule]  8KB each
    __shared__ uint4 sV[2][64 * 8];  // [buf][d][key-granule] 8KB each

    const int t = threadIdx.x;
    const int lane = t & 63, w = t >> 6;
    const int l5 = lane & 31, hi = lane >> 5;
    const int n = blockIdx.z, h = blockIdx.y;
    const int q0 = blockIdx.x * 128;
    const size_t hoff = ((size_t)n * HEADS + h) * (size_t)(LSEQ * HD);
    const unsigned short* Kh = Kp + hoff;
    const unsigned short* Vh = Vt + hoff;

    bf16x8 qf[4];
    {
        const uint4* qg = (const uint4*)(Qp + hoff + (size_t)(q0 + w * 32 + l5) * HD);
        #pragma unroll
        for (int kc = 0; kc < 4; ++kc) qf[kc] = as_bf16x8(qg[kc * 2 + hi]);
    }

    f32x16 Oa0, Oa1;
    #pragma unroll
    for (int i = 0; i < 16; ++i) { Oa0[i] = 0.f; Oa1[i] = 0.f; }
    float ls0 = 0.f, ls1 = 0.f;

    // pre-swizzled source constants: LDS slot (row, g) holds global granule
    // g ^ SW(row), SW(row) = (row ^ (row>>3)) & 7.  Slots t and t+256 sit at
    // rows r0 and r0+32, whose SW differ -> two constants.
    const int r0  = t >> 3;                                   // row 0..31
    const int g0a = (t & 7) ^ ((r0 ^ (r0 >> 3)) & 7);         // SW(r0)
    const int g0b = (t & 7) ^ (((r0 + 32) ^ ((r0 + 32) >> 3)) & 7); // SW(r0+32)
    const uint4* gK = (const uint4*)Kh;
    const uint4* gV = (const uint4*)Vh;          // V^T: 256 uint4 per d-row

    #define STAGE(TILE, BUF)                                                        \
        do {                                                                        \
            int kb_ = (TILE) * 64;                                                  \
            gload_lds16(gK + (size_t)(kb_ + r0) * 8 + g0a,       &sK[BUF][t]);      \
            gload_lds16(gK + (size_t)(kb_ + r0 + 32) * 8 + g0b,  &sK[BUF][t + 256]);\
            gload_lds16(gV + (size_t)r0 * 256 + (kb_ >> 3) + g0a, &sV[BUF][t]);     \
            gload_lds16(gV + (size_t)(r0 + 32) * 256 + (kb_ >> 3) + g0b,            \
                        &sV[BUF][t + 256]);                                         \
        } while (0)

    STAGE(0, 0);
    int cur = 0;

    for (int tt = 0; tt < LSEQ / 64; ++tt) {
        if (tt + 1 < LSEQ / 64) {
            STAGE(tt + 1, cur ^ 1);
            asm volatile("s_waitcnt vmcnt(4)" ::: "memory");
        } else {
            asm volatile("s_waitcnt vmcnt(0)" ::: "memory");
        }
        __builtin_amdgcn_s_barrier();

        #pragma unroll
        for (int tc = 0; tc < 2; ++tc) {
            f32x16 c;
            #pragma unroll
            for (int i = 0; i < 16; ++i) c[i] = 0.f;
            int key = tc * 32 + l5;
            const int ksw = (key ^ (key >> 3)) & 7;           // SW(key)
            __builtin_amdgcn_s_setprio(1);
            #pragma unroll
            for (int kc = 0; kc < 4; ++kc) {
                bf16x8 kf = as_bf16x8(sK[cur][key * 8 + ((kc * 2 + hi) ^ ksw)]);
                c = __builtin_amdgcn_mfma_f32_32x32x16_bf16(kf, qf[kc], c, 0, 0, 0);
            }
            __builtin_amdgcn_s_setprio(0);

            // exp2 + pack adjacent key pairs to bf16 words, sum in fp32.
            unsigned pw[8];
            #pragma unroll
            for (int g = 0; g < 4; ++g) {
                float p0 = exp2f(c[4 * g]);
                float p1 = exp2f(c[4 * g + 1]);
                float p2 = exp2f(c[4 * g + 2]);
                float p3 = exp2f(c[4 * g + 3]);
                ls0 += (p0 + p1);
                ls1 += (p2 + p3);
                asm("v_cvt_pk_bf16_f32 %0, %1, %2" : "=v"(pw[2 * g])     : "v"(p0), "v"(p1));
                asm("v_cvt_pk_bf16_f32 %0, %1, %2" : "=v"(pw[2 * g + 1]) : "v"(p2), "v"(p3));
            }
            // cross-half exchange: swap lanes 32-63 of dst with 0-31 of src.
            asm("v_permlane32_swap_b32 %0, %1" : "+v"(pw[0]), "+v"(pw[2]));
            asm("v_permlane32_swap_b32 %0, %1" : "+v"(pw[1]), "+v"(pw[3]));
            asm("v_permlane32_swap_b32 %0, %1" : "+v"(pw[4]), "+v"(pw[6]));
            asm("v_permlane32_swap_b32 %0, %1" : "+v"(pw[5]), "+v"(pw[7]));

            const int vswa = (l5 ^ (l5 >> 3)) & 7;            // SW(l5)
            const int vswb = vswa ^ 4 ^ ((l5 >> 3) == ((l5 + 0) >> 3) ? 0 : 0); // placeholder, computed below
            (void)vswb;
            const int vswb2 = ((32 + l5) ^ ((32 + l5) >> 3)) & 7; // SW(32+l5)
            __builtin_amdgcn_s_setprio(1);
            #pragma unroll
            for (int win = 0; win < 2; ++win) {
                union { unsigned u[4]; bf16x8 b; } pf;
                pf.u[0] = pw[4 * win];
                pf.u[1] = pw[4 * win + 1];
                pf.u[2] = pw[4 * win + 2];
                pf.u[3] = pw[4 * win + 3];
                int vg = tc * 4 + (win << 1) + hi;
                bf16x8 v0 = as_bf16x8(sV[cur][ l5       * 8 + (vg ^ vswa)]);
                Oa0 = __builtin_amdgcn_mfma_f32_32x32x16_bf16(pf.b, v0, Oa0, 0, 0, 0);
                bf16x8 v1 = as_bf16x8(sV[cur][(32 + l5) * 8 + (vg ^ vswb2)]);
                Oa1 = __builtin_amdgcn_mfma_f32_32x32x16_bf16(pf.b, v1, Oa1, 0, 0, 0);
            }
            __builtin_amdgcn_s_setprio(0);
        }
        __builtin_amdgcn_s_barrier();
        cur ^= 1;
    }
    #undef STAGE

    float lsum = ls0 + ls1;
    lsum += __shfl_xor(lsum, 32);
    float inv = 1.0f / lsum;
    float* sLf = (float*)&sK[0][0];
    if (hi == 0) sLf[w * 32 + l5] = inv;
    __syncthreads();

    unsigned short* hB = AOh + hoff;
    unsigned short* lB = AOl + hoff;
    #pragma unroll
    for (int r = 0; r < 16; ++r) {
        int qr = (r & 3) + 8 * (r >> 2) + 4 * hi;
        float invq = sLf[w * 32 + qr];
        size_t row = (size_t)(q0 + w * 32 + qr) * HD;
        float o0 = Oa0[r] * invq;
        float o1 = Oa1[r] * invq;
        unsigned short h0 = bf16r(o0), h1 = bf16r(o1);
        hB[row +      l5] = h0;
        hB[row + 32 + l5] = h1;
        lB[row +      l5] = bf16r(o0 - bfh2f(h0));
        lB[row + 32 + l5] = bf16r(o1 - bfh2f(h1));
    }
}

// ---------------------------------------------------------------------------
// Kernel 2.5: split Wo into bf16 hi/lo (unchanged).
// ---------------------------------------------------------------------------
__global__ __launch_bounds__(256) void wsplit_kernel(
    const float* __restrict__ Wo,
    unsigned short* __restrict__ Woh, unsigned short* __restrict__ Wol)
{
    int i = blockIdx.x * 256 + threadIdx.x;
    float4 v = ((const float4*)Wo)[i];
    ushort4 h, l;
    h.x = bf16r(v.x); l.x = bf16r(v.x - bfh2f(h.x));
    h.y = bf16r(v.y); l.y = bf16r(v.y - bfh2f(h.y));
    h.z = bf16r(v.z); l.z = bf16r(v.z - bfh2f(h.z));
    h.w = bf16r(v.w); l.w = bf16r(v.w - bfh2f(h.w));
    ((ushort4*)Woh)[i] = h;
    ((ushort4*)Wol)[i] = l;
}

// ---------------------------------------------------------------------------
// Kernel 3: output projection, split-bf16 MFMA GEMM (unchanged).
// ---------------------------------------------------------------------------
__global__ __launch_bounds__(256, 2) void outproj_kernel(
    const unsigned short* __restrict__ AOh, const unsigned short* __restrict__ AOl,
    const unsigned short* __restrict__ Woh, const unsigned short* __restrict__ Wol,
    const float* __restrict__ bo, float* __restrict__ out)
{
    __shared__ uint4 sAh[1024];
    __shared__ uint4 sAl[1024];
    __shared__ uint4 sBh[1024];
    __shared__ uint4 sBl[1024];

    const int t = threadIdx.x;
    const int lane = t & 63, w = t >> 6;
    const int l5 = lane & 31, hi = lane >> 5;
    const int m0 = blockIdx.x * 128;
    const int e0 = blockIdx.y * 128;
    const int n  = m0 >> 11, l0 = m0 & 2047;
    const int mr = (w & 1) * 64, nc = (w >> 1) * 64;

    f32x16 acc[2][2];
    #pragma unroll
    for (int a = 0; a < 2; ++a)
        #pragma unroll
        for (int b = 0; b < 2; ++b)
            #pragma unroll
            for (int i = 0; i < 16; ++i) acc[a][b][i] = 0.f;

    for (int hh = 0; hh < 16; ++hh) {
        const unsigned short* Ah = AOh + ((((size_t)n * HEADS + hh) * LSEQ) + l0) * HD;
        const unsigned short* Al = AOl + ((((size_t)n * HEADS + hh) * LSEQ) + l0) * HD;
        #pragma unroll
        for (int i = 0; i < 4; ++i) {
            int g = t + i * 256;
            gload_lds16(Ah + g * 8, sAh + g);
            gload_lds16(Al + g * 8, sAl + g);
            int e = g >> 3, gf = g & 7;
            size_t boff = (size_t)(e0 + e) * EMBED + hh * 64 + gf * 8;
            gload_lds16(Woh + boff, sBh + g);
            gload_lds16(Wol + boff, sBl + g);
        }
        __syncthreads();

        #pragma unroll
        for (int s = 0; s < 4; ++s) {
            int gcol = s * 2 + hi;
            bf16x8 ah0 = as_bf16x8(sAh[(mr +      l5) * 8 + gcol]);
            bf16x8 ah1 = as_bf16x8(sAh[(mr + 32 + l5) * 8 + gcol]);
            bf16x8 al0 = as_bf16x8(sAl[(mr +      l5) * 8 + gcol]);
            bf16x8 al1 = as_bf16x8(sAl[(mr + 32 + l5) * 8 + gcol]);
            bf16x8 bh0 = as_bf16x8(sBh[(nc +      l5) * 8 + gcol]);
            bf16x8 bh1 = as_bf16x8(sBh[(nc + 32 + l5) * 8 + gcol]);
            bf16x8 bl0 = as_bf16x8(sBl[(nc +      l5) * 8 + gcol]);
            bf16x8 bl1 = as_bf16x8(sBl[(nc + 32 + l5) * 8 + gcol]);

            acc[0][0] = __builtin_amdgcn_mfma_f32_32x32x16_bf16(ah0, bh0, acc[0][0], 0, 0, 0);
            acc[0][1] = __builtin_amdgcn_mfma_f32_32x32x16_bf16(ah0, bh1, acc[0][1], 0, 0, 0);
            acc[1][0] = __builtin_amdgcn_mfma_f32_32x32x16_bf16(ah1, bh0, acc[1][0], 0, 0, 0);
            acc[1][1] = __builtin_amdgcn_mfma_f32_32x32x16_bf16(ah1, bh1, acc[1][1], 0, 0, 0);

            acc[0][0] = __builtin_amdgcn_mfma_f32_32x32x16_bf16(ah0, bl0, acc[0][0], 0, 0, 0);
            acc[0][1] = __builtin_amdgcn_mfma_f32_32x32x16_bf16(ah0, bl1, acc[0][1], 0, 0, 0);
            acc[1][0] = __builtin_amdgcn_mfma_f32_32x32x16_bf16(ah1, bl0, acc[1][0], 0, 0, 0);
            acc[1][1] = __builtin_amdgcn_mfma_f32_32x32x16_bf16(ah1, bl1, acc[1][1], 0, 0, 0);

            acc[0][0] = __builtin_amdgcn_mfma_f32_32x32x16_bf16(al0, bh0, acc[0][0], 0, 0, 0);
            acc[0][1] = __builtin_amdgcn_mfma_f32_32x32x16_bf16(al0, bh1, acc[0][1], 0, 0, 0);
            acc[1][0] = __builtin_amdgcn_mfma_f32_32x32x16_bf16(al1, bh0, acc[1][0], 0, 0, 0);
            acc[1][1] = __builtin_amdgcn_mfma_f32_32x32x16_bf16(al1, bh1, acc[1][1], 0, 0, 0);
        }
        __syncthreads();
    }

    float b0 = bo[e0 + nc + l5];
    float b1 = bo[e0 + nc + 32 + l5];
    #pragma unroll
    for (int ti = 0; ti < 2; ++ti) {
        #pragma unroll
        for (int r = 0; r < 16; ++r) {
            int row = m0 + mr + ti * 32 + (r & 3) + 8 * (r >> 2) + 4 * hi;
            float* o = out + (size_t)row * EMBED + e0 + nc;
            o[l5]      = acc[ti][0][r] + b0;
            o[32 + l5] = acc[ti][1][r] + b1;
        }
    }
}

// ---------------------------------------------------------------------------
extern "C" void kernel_launch(void* const* d_in, const int* in_sizes, int n_in,
                              void* d_out, int out_size, void* d_ws, size_t ws_size,
                              hipStream_t stream)
{
    const float* values  = (const float*)d_in[0];
    const float* keys    = (const float*)d_in[1];
    const float* queries = (const float*)d_in[2];
    const float* Wv      = (const float*)d_in[3];
    const float* Wk      = (const float*)d_in[4];
    const float* Wq      = (const float*)d_in[5];
    const float* Wo      = (const float*)d_in[6];
    const float* bo      = (const float*)d_in[7];
    float* out = (float*)d_out;

    const size_t bufElems = (size_t)NB * HEADS * LSEQ * HD;   // 8,388,608
    unsigned short* Qp  = (unsigned short*)d_ws;
    unsigned short* Kp  = Qp  + bufElems;
    unsigned short* Vt  = Kp  + bufElems;
    unsigned short* AOh = Vt  + bufElems;
    unsigned short* AOl = AOh + bufElems;
    unsigned short* Woh = AOl + bufElems;
    unsigned short* Wol = Woh + (size_t)EMBED * EMBED;

    wsplit_kernel<<<dim3(1024), 256, 0, stream>>>(Wo, Woh, Wol);
    proj_kernel<<<dim3(NB * 16, HEADS), 256, 0, stream>>>(values, keys, queries, Wv, Wk, Wq, Vt, Kp, Qp);
    attn_kernel<<<dim3(LSEQ / 128, HEADS, NB), 256, 0, stream>>>(Qp, Kp, Vt, AOh, AOl);
    outproj_kernel<<<dim3(NB * LSEQ / 128, EMBED / 128), 256, 0, stream>>>(AOh, AOl, Woh, Wol, bo, out);
}

// Round 5
// 362.979 us; speedup vs baseline: 1.0546x; 1.0546x over previous
//
#include <hip/hip_runtime.h>
#include <math.h>

#define EMBED 1024
#define HEADS 16
#define HD    64
#define NB    4
#define LSEQ  2048

typedef __attribute__((ext_vector_type(8))) short bf16x8;
typedef __attribute__((ext_vector_type(16))) float f32x16;

typedef __attribute__((address_space(1))) void as1_void;
typedef __attribute__((address_space(3))) void as3_void;

__device__ __forceinline__ void gload_lds16(const void* g, void* l) {
    __builtin_amdgcn_global_load_lds((const as1_void*)g, (as3_void*)l, 16, 0, 0);
}

__device__ inline bf16x8 as_bf16x8(uint4 u) {
    union { uint4 u; bf16x8 b; } c; c.u = u; return c.b;
}
// round-to-nearest-even fp32 -> bf16 (raw ushort); finite inputs only
__device__ inline unsigned short bf16r(float x) {
    unsigned u = __float_as_uint(x);
    u += 0x7fffu + ((u >> 16) & 1u);
    return (unsigned short)(u >> 16);
}
__device__ inline float bfh2f(unsigned short h) {
    return __uint_as_float(((unsigned)h) << 16);
}
// split two floats into packed hi/lo bf16 words
__device__ inline void split2(float x, float y, unsigned& hw, unsigned& lw) {
    unsigned short hx = bf16r(x), hy = bf16r(y);
    unsigned short lx = bf16r(x - bfh2f(hx)), ly = bf16r(y - bfh2f(hy));
    hw = (unsigned)hx | ((unsigned)hy << 16);
    lw = (unsigned)lx | ((unsigned)ly << 16);
}

// ---------------------------------------------------------------------------
// Kernel 1: QKV projections as split-bf16 MFMA GEMM.
// R10 change (T14): next phase's X (8 float4) and W (4 float4) are loaded
// into registers during the current phase's MFMA+epilogue, instead of being
// serially exposed at the top of each phase.  The pre-MFMA barrier is raw
// (lgkmcnt(0) only) so the prefetch loads stay in flight across it.
// ---------------------------------------------------------------------------
__global__ __launch_bounds__(256, 3) void proj_kernel(
    const float* __restrict__ Xv, const float* __restrict__ Xk, const float* __restrict__ Xq,
    const float* __restrict__ Wv, const float* __restrict__ Wk, const float* __restrict__ Wq,
    unsigned short* __restrict__ Vt, unsigned short* __restrict__ Kp, unsigned short* __restrict__ Qp)
{
    __shared__ uint4 sXh[128 * 8];   // [token][granule of 8 dims]  16KB
    __shared__ uint4 sXl[128 * 8];   // 16KB
    __shared__ uint4 sWh[64 * 8];    // [e][granule of 8 dims]       8KB
    __shared__ uint4 sWl[64 * 8];    //                              8KB

    const int t = threadIdx.x;
    const int lane = t & 63, w = t >> 6;
    const int l5 = lane & 31, hi = lane >> 5;
    const int h  = blockIdx.y;
    const int n  = blockIdx.x >> 4;
    const int l0 = (blockIdx.x & 15) * 128;

    const float QSC = 1.44269504088896341f / 32.0f;
    const float* Xs[3] = {Xv, Xk, Xq};
    const float* Ws[3] = {Wv, Wk, Wq};

    const int frow = t >> 4;        // staging: row group 0..15
    const int fcol = t & 15;        // float4 index within 64-dim row

    float4 xr[8];                   // prefetched X tile slice
    float4 wr[4];                   // prefetched W slice

    // ---- prologue: load phase-0 operands into registers ----
    {
        const float* xb = Xs[0] + ((size_t)(n * LSEQ + l0 + frow)) * EMBED + h * HD + fcol * 4;
        #pragma unroll
        for (int i = 0; i < 8; ++i) xr[i] = *(const float4*)(xb + (size_t)i * 16 * EMBED);
        const float* wb0 = Ws[0] + (size_t)t * 8;
        const float* wb1 = Ws[0] + (size_t)(t + 256) * 8;
        wr[0] = *(const float4*)(wb0);
        wr[1] = *(const float4*)(wb0 + 4);
        wr[2] = *(const float4*)(wb1);
        wr[3] = *(const float4*)(wb1 + 4);
    }

    for (int p = 0; p < 3; ++p) {
        __syncthreads();            // prev MFMA reads done; prefetch completed
        // ---- split + write X tile from regs (swizzled) ----
        {
            unsigned short* dh = (unsigned short*)sXh;
            unsigned short* dl = (unsigned short*)sXl;
            #pragma unroll
            for (int i = 0; i < 8; ++i) {
                int row = frow + i * 16;
                int gg = fcol >> 1, s8 = (fcol & 1) * 4;
                int idx = row * 64 + ((gg ^ (row & 7)) * 8) + s8;
                uint2 hv, lv;
                split2(xr[i].x, xr[i].y, hv.x, lv.x);
                split2(xr[i].z, xr[i].w, hv.y, lv.y);
                *(uint2*)(dh + idx) = hv;
                *(uint2*)(dl + idx) = lv;
            }
        }
        // ---- split + write W from regs (swizzled) ----
        #pragma unroll
        for (int i = 0; i < 2; ++i) {
            int u = t + 256 * i;
            int e = u >> 3, g = u & 7;
            uint4 hq, lq;
            split2(wr[2 * i].x, wr[2 * i].y, hq.x, lq.x);
            split2(wr[2 * i].z, wr[2 * i].w, hq.y, lq.y);
            split2(wr[2 * i + 1].x, wr[2 * i + 1].y, hq.z, lq.z);
            split2(wr[2 * i + 1].z, wr[2 * i + 1].w, hq.w, lq.w);
            int idx = e * 8 + (g ^ (e & 7));
            sWh[idx] = hq;
            sWl[idx] = lq;
        }
        // ---- issue next phase's loads; they fly over MFMA+epilogue ----
        if (p < 2) {
            const float* xb = Xs[p + 1] + ((size_t)(n * LSEQ + l0 + frow)) * EMBED + h * HD + fcol * 4;
            #pragma unroll
            for (int i = 0; i < 8; ++i) xr[i] = *(const float4*)(xb + (size_t)i * 16 * EMBED);
            const float* wb0 = Ws[p + 1] + (size_t)t * 8;
            const float* wb1 = Ws[p + 1] + (size_t)(t + 256) * 8;
            wr[0] = *(const float4*)(wb0);
            wr[1] = *(const float4*)(wb0 + 4);
            wr[2] = *(const float4*)(wb1);
            wr[3] = *(const float4*)(wb1 + 4);
        }
        asm volatile("s_waitcnt lgkmcnt(0)" ::: "memory");
        __builtin_amdgcn_s_barrier();

        // ---- MFMA: per wave, 32-token tile x (two 32-wide e-tiles) ----
        f32x16 acc0, acc1;
        #pragma unroll
        for (int i = 0; i < 16; ++i) { acc0[i] = 0.f; acc1[i] = 0.f; }

        const int xrow = w * 32 + l5;
        const int w0r = l5, w1r = 32 + l5;
        #pragma unroll
        for (int kc = 0; kc < 4; ++kc) {
            int gsel = kc * 2 + hi;
            bf16x8 xh = as_bf16x8(sXh[xrow * 8 + (gsel ^ (xrow & 7))]);
            bf16x8 xl = as_bf16x8(sXl[xrow * 8 + (gsel ^ (xrow & 7))]);
            bf16x8 wh0 = as_bf16x8(sWh[w0r * 8 + (gsel ^ (w0r & 7))]);
            bf16x8 wl0 = as_bf16x8(sWl[w0r * 8 + (gsel ^ (w0r & 7))]);
            bf16x8 wh1 = as_bf16x8(sWh[w1r * 8 + (gsel ^ (w1r & 7))]);
            bf16x8 wl1 = as_bf16x8(sWl[w1r * 8 + (gsel ^ (w1r & 7))]);
            if (p == 0) {
                // V^T = W X^T : A=W-frag (rows e), B=X-frag (cols token)
                acc0 = __builtin_amdgcn_mfma_f32_32x32x16_bf16(wh0, xh, acc0, 0, 0, 0);
                acc0 = __builtin_amdgcn_mfma_f32_32x32x16_bf16(wh0, xl, acc0, 0, 0, 0);
                acc0 = __builtin_amdgcn_mfma_f32_32x32x16_bf16(wl0, xh, acc0, 0, 0, 0);
                acc1 = __builtin_amdgcn_mfma_f32_32x32x16_bf16(wh1, xh, acc1, 0, 0, 0);
                acc1 = __builtin_amdgcn_mfma_f32_32x32x16_bf16(wh1, xl, acc1, 0, 0, 0);
                acc1 = __builtin_amdgcn_mfma_f32_32x32x16_bf16(wl1, xh, acc1, 0, 0, 0);
            } else {
                // C = X W^T : A=X-frag (rows token), B=W-frag (cols e)
                acc0 = __builtin_amdgcn_mfma_f32_32x32x16_bf16(xh, wh0, acc0, 0, 0, 0);
                acc0 = __builtin_amdgcn_mfma_f32_32x32x16_bf16(xh, wl0, acc0, 0, 0, 0);
                acc0 = __builtin_amdgcn_mfma_f32_32x32x16_bf16(xl, wh0, acc0, 0, 0, 0);
                acc1 = __builtin_amdgcn_mfma_f32_32x32x16_bf16(xh, wh1, acc1, 0, 0, 0);
                acc1 = __builtin_amdgcn_mfma_f32_32x32x16_bf16(xh, wl1, acc1, 0, 0, 0);
                acc1 = __builtin_amdgcn_mfma_f32_32x32x16_bf16(xl, wh1, acc1, 0, 0, 0);
            }
        }

        // ---- epilogue ----
        if (p == 0) {
            // C rows = e, cols = token (V^T): coalesced Vt [N,H,D,L] stores
            unsigned short* vb = Vt + (((size_t)(n * HEADS + h)) * HD) * LSEQ + l0 + w * 32 + l5;
            #pragma unroll
            for (int r = 0; r < 16; ++r) {
                int er = (r & 3) + 8 * (r >> 2) + 4 * hi;
                vb[(size_t)er * LSEQ]        = bf16r(acc0[r]);
                vb[(size_t)(32 + er) * LSEQ] = bf16r(acc1[r]);
            }
        } else {
            unsigned short* dst = (p == 1) ? Kp : Qp;
            float sc = (p == 2) ? QSC : 1.0f;
            unsigned short* db = dst + (((size_t)(n * HEADS + h)) * LSEQ + l0 + w * 32) * HD;
            #pragma unroll
            for (int r = 0; r < 16; ++r) {
                int tok = (r & 3) + 8 * (r >> 2) + 4 * hi;
                db[(size_t)tok * HD + l5]      = bf16r(acc0[r] * sc);
                db[(size_t)tok * HD + 32 + l5] = bf16r(acc1[r] * sc);
            }
        }
    }
}

// ---------------------------------------------------------------------------
// Kernel 2: MFMA flash attention, S^T orientation — exact R8 revert.
// (R9's deeper swizzle removed all 8.39e6 bank conflicts but cost +4us:
// the conflicts were fully hidden; the extra index VALU was not.)
// ---------------------------------------------------------------------------
__global__ __launch_bounds__(256, 4) void attn_kernel(
    const unsigned short* __restrict__ Qp, const unsigned short* __restrict__ Kp,
    const unsigned short* __restrict__ Vt,
    unsigned short* __restrict__ AOh, unsigned short* __restrict__ AOl)
{
    __shared__ uint4 sK[2][64 * 8];  // [buf][key][granule]  8KB each
    __shared__ uint4 sV[2][64 * 8];  // [buf][d][key-granule] 8KB each

    const int t = threadIdx.x;
    const int lane = t & 63, w = t >> 6;
    const int l5 = lane & 31, hi = lane >> 5;
    const int n = blockIdx.z, h = blockIdx.y;
    const int q0 = blockIdx.x * 128;
    const size_t hoff = ((size_t)n * HEADS + h) * (size_t)(LSEQ * HD);
    const unsigned short* Kh = Kp + hoff;
    const unsigned short* Vh = Vt + hoff;

    bf16x8 qf[4];
    {
        const uint4* qg = (const uint4*)(Qp + hoff + (size_t)(q0 + w * 32 + l5) * HD);
        #pragma unroll
        for (int kc = 0; kc < 4; ++kc) qf[kc] = as_bf16x8(qg[kc * 2 + hi]);
    }

    f32x16 Oa0, Oa1;
    #pragma unroll
    for (int i = 0; i < 16; ++i) { Oa0[i] = 0.f; Oa1[i] = 0.f; }
    float ls0 = 0.f, ls1 = 0.f;

    // pre-swizzled source constants: LDS slot idx holds global granule
    // ((idx>>3), (idx&7)^((idx>>3)&7)); rows for slots t and t+256 differ by
    // 32 so the XOR term is identical.
    const int r0 = t >> 3;                       // key-row / d-row 0..31
    const int g0 = (t & 7) ^ (r0 & 7);           // swizzled granule
    const uint4* gK = (const uint4*)Kh;
    const uint4* gV = (const uint4*)Vh;          // V^T: 256 uint4 per d-row

    #define STAGE(TILE, BUF)                                                        \
        do {                                                                        \
            int kb_ = (TILE) * 64;                                                  \
            gload_lds16(gK + (size_t)(kb_ + r0) * 8 + g0,        &sK[BUF][t]);      \
            gload_lds16(gK + (size_t)(kb_ + r0 + 32) * 8 + g0,   &sK[BUF][t + 256]);\
            gload_lds16(gV + (size_t)r0 * 256 + (kb_ >> 3) + g0, &sV[BUF][t]);      \
            gload_lds16(gV + (size_t)(r0 + 32) * 256 + (kb_ >> 3) + g0,             \
                        &sV[BUF][t + 256]);                                         \
        } while (0)

    STAGE(0, 0);
    int cur = 0;

    for (int tt = 0; tt < LSEQ / 64; ++tt) {
        if (tt + 1 < LSEQ / 64) {
            STAGE(tt + 1, cur ^ 1);
            asm volatile("s_waitcnt vmcnt(4)" ::: "memory");
        } else {
            asm volatile("s_waitcnt vmcnt(0)" ::: "memory");
        }
        __builtin_amdgcn_s_barrier();

        #pragma unroll
        for (int tc = 0; tc < 2; ++tc) {
            f32x16 c;
            #pragma unroll
            for (int i = 0; i < 16; ++i) c[i] = 0.f;
            int key = tc * 32 + l5;
            __builtin_amdgcn_s_setprio(1);
            #pragma unroll
            for (int kc = 0; kc < 4; ++kc) {
                bf16x8 kf = as_bf16x8(sK[cur][key * 8 + ((kc * 2 + hi) ^ (l5 & 7))]);
                c = __builtin_amdgcn_mfma_f32_32x32x16_bf16(kf, qf[kc], c, 0, 0, 0);
            }
            __builtin_amdgcn_s_setprio(0);

            // exp2 + pack adjacent key pairs to bf16 words, sum in fp32.
            unsigned pw[8];
            #pragma unroll
            for (int g = 0; g < 4; ++g) {
                float p0 = exp2f(c[4 * g]);
                float p1 = exp2f(c[4 * g + 1]);
                float p2 = exp2f(c[4 * g + 2]);
                float p3 = exp2f(c[4 * g + 3]);
                ls0 += (p0 + p1);
                ls1 += (p2 + p3);
                asm("v_cvt_pk_bf16_f32 %0, %1, %2" : "=v"(pw[2 * g])     : "v"(p0), "v"(p1));
                asm("v_cvt_pk_bf16_f32 %0, %1, %2" : "=v"(pw[2 * g + 1]) : "v"(p2), "v"(p3));
            }
            // cross-half exchange: swap lanes 32-63 of dst with 0-31 of src.
            asm("v_permlane32_swap_b32 %0, %1" : "+v"(pw[0]), "+v"(pw[2]));
            asm("v_permlane32_swap_b32 %0, %1" : "+v"(pw[1]), "+v"(pw[3]));
            asm("v_permlane32_swap_b32 %0, %1" : "+v"(pw[4]), "+v"(pw[6]));
            asm("v_permlane32_swap_b32 %0, %1" : "+v"(pw[5]), "+v"(pw[7]));

            __builtin_amdgcn_s_setprio(1);
            #pragma unroll
            for (int win = 0; win < 2; ++win) {
                union { unsigned u[4]; bf16x8 b; } pf;
                pf.u[0] = pw[4 * win];
                pf.u[1] = pw[4 * win + 1];
                pf.u[2] = pw[4 * win + 2];
                pf.u[3] = pw[4 * win + 3];
                int vg = tc * 4 + (win << 1) + hi;
                bf16x8 v0 = as_bf16x8(sV[cur][ l5       * 8 + (vg ^ (l5 & 7))]);
                Oa0 = __builtin_amdgcn_mfma_f32_32x32x16_bf16(pf.b, v0, Oa0, 0, 0, 0);
                bf16x8 v1 = as_bf16x8(sV[cur][(32 + l5) * 8 + (vg ^ (l5 & 7))]);
                Oa1 = __builtin_amdgcn_mfma_f32_32x32x16_bf16(pf.b, v1, Oa1, 0, 0, 0);
            }
            __builtin_amdgcn_s_setprio(0);
        }
        __builtin_amdgcn_s_barrier();
        cur ^= 1;
    }
    #undef STAGE

    float lsum = ls0 + ls1;
    lsum += __shfl_xor(lsum, 32);
    float inv = 1.0f / lsum;
    float* sLf = (float*)&sK[0][0];
    if (hi == 0) sLf[w * 32 + l5] = inv;
    __syncthreads();

    unsigned short* hB = AOh + hoff;
    unsigned short* lB = AOl + hoff;
    #pragma unroll
    for (int r = 0; r < 16; ++r) {
        int qr = (r & 3) + 8 * (r >> 2) + 4 * hi;
        float invq = sLf[w * 32 + qr];
        size_t row = (size_t)(q0 + w * 32 + qr) * HD;
        float o0 = Oa0[r] * invq;
        float o1 = Oa1[r] * invq;
        unsigned short h0 = bf16r(o0), h1 = bf16r(o1);
        hB[row +      l5] = h0;
        hB[row + 32 + l5] = h1;
        lB[row +      l5] = bf16r(o0 - bfh2f(h0));
        lB[row + 32 + l5] = bf16r(o1 - bfh2f(h1));
    }
}

// ---------------------------------------------------------------------------
// Kernel 2.5: split Wo into bf16 hi/lo (unchanged).
// ---------------------------------------------------------------------------
__global__ __launch_bounds__(256) void wsplit_kernel(
    const float* __restrict__ Wo,
    unsigned short* __restrict__ Woh, unsigned short* __restrict__ Wol)
{
    int i = blockIdx.x * 256 + threadIdx.x;
    float4 v = ((const float4*)Wo)[i];
    ushort4 h, l;
    h.x = bf16r(v.x); l.x = bf16r(v.x - bfh2f(h.x));
    h.y = bf16r(v.y); l.y = bf16r(v.y - bfh2f(h.y));
    h.z = bf16r(v.z); l.z = bf16r(v.z - bfh2f(h.z));
    h.w = bf16r(v.w); l.w = bf16r(v.w - bfh2f(h.w));
    ((ushort4*)Woh)[i] = h;
    ((ushort4*)Wol)[i] = l;
}

// ---------------------------------------------------------------------------
// Kernel 3: output projection, split-bf16 MFMA GEMM.
// R10 rebuild with the R8-attn recipe: the old version staged 64KB per head
// with a full vmcnt(0) drain at each of 16 __syncthreads at 2 blocks/CU —
// fully synchronous, ~5x above roofline.  Now: K-chunk 32 (half-head),
// 2x 32KB ping-pong buffers (total 64KB, still 2 blocks/CU), global_load_lds
// staging with pre-swizzled source (granule g -> g^(row&3); reads are
// conflict-free: 64 lanes cover all 8 16B-positions uniformly), counted
// s_waitcnt vmcnt(8) + raw barriers so next chunk's loads fly over MFMA,
// setprio around the MFMA cluster.
// ---------------------------------------------------------------------------
__global__ __launch_bounds__(256, 2) void outproj_kernel(
    const unsigned short* __restrict__ AOh, const unsigned short* __restrict__ AOl,
    const unsigned short* __restrict__ Woh, const unsigned short* __restrict__ Wol,
    const float* __restrict__ bo, float* __restrict__ out)
{
    __shared__ uint4 sAh[2][512];   // [buf][row*4 + g]  8KB each
    __shared__ uint4 sAl[2][512];
    __shared__ uint4 sBh[2][512];
    __shared__ uint4 sBl[2][512];

    const int t = threadIdx.x;
    const int lane = t & 63, w = t >> 6;
    const int l5 = lane & 31, hi = lane >> 5;
    const int m0 = blockIdx.x * 128;
    const int e0 = blockIdx.y * 128;
    const int n  = m0 >> 11, l0 = m0 & 2047;
    const int mr = (w & 1) * 64, nc = (w >> 1) * 64;

    // staging: thread t covers slots t (row ar0) and t+256 (row ar0+64).
    // slot (row,g) holds source granule g ^ (row&3); rows differ by 64 so
    // the XOR constant is shared.
    const int ar0 = t >> 2;
    const int ag0 = (t & 3) ^ (ar0 & 3);

    #define OSTAGE(C, BUF)                                                            \
        do {                                                                          \
            int hh_ = (C) >> 1, hf_ = (C) & 1;                                        \
            const uint4* gAh_ = (const uint4*)(AOh) +                                 \
                (((size_t)n * HEADS + hh_) * LSEQ + l0) * 8;                          \
            const uint4* gAl_ = (const uint4*)(AOl) +                                 \
                (((size_t)n * HEADS + hh_) * LSEQ + l0) * 8;                          \
            const uint4* gBh_ = (const uint4*)(Woh) + (size_t)e0 * 128 + hh_ * 8;     \
            const uint4* gBl_ = (const uint4*)(Wol) + (size_t)e0 * 128 + hh_ * 8;     \
            gload_lds16(gAh_ + (size_t)ar0 * 8 + hf_ * 4 + ag0,        &sAh[BUF][t]);       \
            gload_lds16(gAh_ + (size_t)(ar0 + 64) * 8 + hf_ * 4 + ag0, &sAh[BUF][t + 256]); \
            gload_lds16(gAl_ + (size_t)ar0 * 8 + hf_ * 4 + ag0,        &sAl[BUF][t]);       \
            gload_lds16(gAl_ + (size_t)(ar0 + 64) * 8 + hf_ * 4 + ag0, &sAl[BUF][t + 256]); \
            gload_lds16(gBh_ + (size_t)ar0 * 128 + hf_ * 4 + ag0,        &sBh[BUF][t]);       \
            gload_lds16(gBh_ + (size_t)(ar0 + 64) * 128 + hf_ * 4 + ag0, &sBh[BUF][t + 256]); \
            gload_lds16(gBl_ + (size_t)ar0 * 128 + hf_ * 4 + ag0,        &sBl[BUF][t]);       \
            gload_lds16(gBl_ + (size_t)(ar0 + 64) * 128 + hf_ * 4 + ag0, &sBl[BUF][t + 256]); \
        } while (0)

    f32x16 acc[2][2];
    #pragma unroll
    for (int a = 0; a < 2; ++a)
        #pragma unroll
        for (int b = 0; b < 2; ++b)
            #pragma unroll
            for (int i = 0; i < 16; ++i) acc[a][b][i] = 0.f;

    OSTAGE(0, 0);
    int cur = 0;

    for (int c = 0; c < 32; ++c) {
        if (c + 1 < 32) {
            OSTAGE(c + 1, cur ^ 1);
            asm volatile("s_waitcnt vmcnt(8)" ::: "memory");
        } else {
            asm volatile("s_waitcnt vmcnt(0)" ::: "memory");
        }
        __builtin_amdgcn_s_barrier();

        __builtin_amdgcn_s_setprio(1);
        #pragma unroll
        for (int s = 0; s < 2; ++s) {
            int gx = (s * 2 + hi) ^ (l5 & 3);
            bf16x8 ah0 = as_bf16x8(sAh[cur][(mr +      l5) * 4 + gx]);
            bf16x8 ah1 = as_bf16x8(sAh[cur][(mr + 32 + l5) * 4 + gx]);
            bf16x8 al0 = as_bf16x8(sAl[cur][(mr +      l5) * 4 + gx]);
            bf16x8 al1 = as_bf16x8(sAl[cur][(mr + 32 + l5) * 4 + gx]);
            bf16x8 bh0 = as_bf16x8(sBh[cur][(nc +      l5) * 4 + gx]);
            bf16x8 bh1 = as_bf16x8(sBh[cur][(nc + 32 + l5) * 4 + gx]);
            bf16x8 bl0 = as_bf16x8(sBl[cur][(nc +      l5) * 4 + gx]);
            bf16x8 bl1 = as_bf16x8(sBl[cur][(nc + 32 + l5) * 4 + gx]);

            acc[0][0] = __builtin_amdgcn_mfma_f32_32x32x16_bf16(ah0, bh0, acc[0][0], 0, 0, 0);
            acc[0][1] = __builtin_amdgcn_mfma_f32_32x32x16_bf16(ah0, bh1, acc[0][1], 0, 0, 0);
            acc[1][0] = __builtin_amdgcn_mfma_f32_32x32x16_bf16(ah1, bh0, acc[1][0], 0, 0, 0);
            acc[1][1] = __builtin_amdgcn_mfma_f32_32x32x16_bf16(ah1, bh1, acc[1][1], 0, 0, 0);

            acc[0][0] = __builtin_amdgcn_mfma_f32_32x32x16_bf16(ah0, bl0, acc[0][0], 0, 0, 0);
            acc[0][1] = __builtin_amdgcn_mfma_f32_32x32x16_bf16(ah0, bl1, acc[0][1], 0, 0, 0);
            acc[1][0] = __builtin_amdgcn_mfma_f32_32x32x16_bf16(ah1, bl0, acc[1][0], 0, 0, 0);
            acc[1][1] = __builtin_amdgcn_mfma_f32_32x32x16_bf16(ah1, bl1, acc[1][1], 0, 0, 0);

            acc[0][0] = __builtin_amdgcn_mfma_f32_32x32x16_bf16(al0, bh0, acc[0][0], 0, 0, 0);
            acc[0][1] = __builtin_amdgcn_mfma_f32_32x32x16_bf16(al0, bh1, acc[0][1], 0, 0, 0);
            acc[1][0] = __builtin_amdgcn_mfma_f32_32x32x16_bf16(al1, bh0, acc[1][0], 0, 0, 0);
            acc[1][1] = __builtin_amdgcn_mfma_f32_32x32x16_bf16(al1, bh1, acc[1][1], 0, 0, 0);
        }
        __builtin_amdgcn_s_setprio(0);
        __builtin_amdgcn_s_barrier();
        cur ^= 1;
    }
    #undef OSTAGE

    float b0 = bo[e0 + nc + l5];
    float b1 = bo[e0 + nc + 32 + l5];
    #pragma unroll
    for (int ti = 0; ti < 2; ++ti) {
        #pragma unroll
        for (int r = 0; r < 16; ++r) {
            int row = m0 + mr + ti * 32 + (r & 3) + 8 * (r >> 2) + 4 * hi;
            float* o = out + (size_t)row * EMBED + e0 + nc;
            o[l5]      = acc[ti][0][r] + b0;
            o[32 + l5] = acc[ti][1][r] + b1;
        }
    }
}

// ---------------------------------------------------------------------------
extern "C" void kernel_launch(void* const* d_in, const int* in_sizes, int n_in,
                              void* d_out, int out_size, void* d_ws, size_t ws_size,
                              hipStream_t stream)
{
    const float* values  = (const float*)d_in[0];
    const float* keys    = (const float*)d_in[1];
    const float* queries = (const float*)d_in[2];
    const float* Wv      = (const float*)d_in[3];
    const float* Wk      = (const float*)d_in[4];
    const float* Wq      = (const float*)d_in[5];
    const float* Wo      = (const float*)d_in[6];
    const float* bo      = (const float*)d_in[7];
    float* out = (float*)d_out;

    const size_t bufElems = (size_t)NB * HEADS * LSEQ * HD;   // 8,388,608
    unsigned short* Qp  = (unsigned short*)d_ws;
    unsigned short* Kp  = Qp  + bufElems;
    unsigned short* Vt  = Kp  + bufElems;
    unsigned short* AOh = Vt  + bufElems;
    unsigned short* AOl = AOh + bufElems;
    unsigned short* Woh = AOl + bufElems;
    unsigned short* Wol = Woh + (size_t)EMBED * EMBED;

    wsplit_kernel<<<dim3(1024), 256, 0, stream>>>(Wo, Woh, Wol);
    proj_kernel<<<dim3(NB * 16, HEADS), 256, 0, stream>>>(values, keys, queries, Wv, Wk, Wq, Vt, Kp, Qp);
    attn_kernel<<<dim3(LSEQ / 128, HEADS, NB), 256, 0, stream>>>(Qp, Kp, Vt, AOh, AOl);
    outproj_kernel<<<dim3(NB * LSEQ / 128, EMBED / 128), 256, 0, stream>>>(AOh, AOl, Woh, Wol, bo, out);
}

// Round 6
// 352.488 us; speedup vs baseline: 1.0860x; 1.0298x over previous
//
#include <hip/hip_runtime.h>
#include <math.h>

#define EMBED 1024
#define HEADS 16
#define HD    64
#define NB    4
#define LSEQ  2048

typedef __attribute__((ext_vector_type(8))) short bf16x8;
typedef __attribute__((ext_vector_type(16))) float f32x16;

typedef __attribute__((address_space(1))) void as1_void;
typedef __attribute__((address_space(3))) void as3_void;

__device__ __forceinline__ void gload_lds16(const void* g, void* l) {
    __builtin_amdgcn_global_load_lds((const as1_void*)g, (as3_void*)l, 16, 0, 0);
}

__device__ inline bf16x8 as_bf16x8(uint4 u) {
    union { uint4 u; bf16x8 b; } c; c.u = u; return c.b;
}
// round-to-nearest-even fp32 -> bf16 (raw ushort); finite inputs only
__device__ inline unsigned short bf16r(float x) {
    unsigned u = __float_as_uint(x);
    u += 0x7fffu + ((u >> 16) & 1u);
    return (unsigned short)(u >> 16);
}
__device__ inline float bfh2f(unsigned short h) {
    return __uint_as_float(((unsigned)h) << 16);
}
// split two floats into packed hi/lo bf16 words
__device__ inline void split2(float x, float y, unsigned& hw, unsigned& lw) {
    unsigned short hx = bf16r(x), hy = bf16r(y);
    unsigned short lx = bf16r(x - bfh2f(hx)), ly = bf16r(y - bfh2f(hy));
    hw = (unsigned)hx | ((unsigned)hy << 16);
    lw = (unsigned)lx | ((unsigned)ly << 16);
}

// ---------------------------------------------------------------------------
// Kernel 1: QKV projections as split-bf16 MFMA GEMM.
// R11 change: the V/K/Q phases become INDEPENDENT BLOCKS (gridDim.z = 3)
// instead of a serial 3-phase loop inside each block.  The phase loop forced
// every wave through stage(350 VALU) -> barrier -> MFMA -> barrier x3 in
// lockstep; with 3072 independent blocks the scheduler overlaps one block's
// staging VALU with another's MFMA.  Prefetch registers removed (lower VGPR).
// LDS 48KB -> 3 blocks/CU.
// ---------------------------------------------------------------------------
__global__ __launch_bounds__(256, 3) void proj_kernel(
    const float* __restrict__ Xv, const float* __restrict__ Xk, const float* __restrict__ Xq,
    const float* __restrict__ Wv, const float* __restrict__ Wk, const float* __restrict__ Wq,
    unsigned short* __restrict__ Vt, unsigned short* __restrict__ Kp, unsigned short* __restrict__ Qp)
{
    __shared__ uint4 sXh[128 * 8];   // [token][granule of 8 dims]  16KB
    __shared__ uint4 sXl[128 * 8];   // 16KB
    __shared__ uint4 sWh[64 * 8];    // [e][granule of 8 dims]       8KB
    __shared__ uint4 sWl[64 * 8];    //                              8KB

    const int t = threadIdx.x;
    const int lane = t & 63, w = t >> 6;
    const int l5 = lane & 31, hi = lane >> 5;
    const int h  = blockIdx.y;
    const int n  = blockIdx.x >> 4;
    const int l0 = (blockIdx.x & 15) * 128;
    const int p  = blockIdx.z;

    const float QSC = 1.44269504088896341f / 32.0f;
    const float* Xp = (p == 0) ? Xv : (p == 1) ? Xk : Xq;
    const float* Wp = (p == 0) ? Wv : (p == 1) ? Wk : Wq;

    const int frow = t >> 4;        // staging: row group 0..15
    const int fcol = t & 15;        // float4 index within 64-dim row

    // ---- stage X tile: 128 rows x 64 dims fp32 -> hi/lo bf16, swizzled ----
    {
        const float* xb = Xp + ((size_t)(n * LSEQ + l0 + frow)) * EMBED + h * HD + fcol * 4;
        unsigned short* dh = (unsigned short*)sXh;
        unsigned short* dl = (unsigned short*)sXl;
        #pragma unroll
        for (int i = 0; i < 8; ++i) {
            int row = frow + i * 16;
            float4 v = *(const float4*)(xb + (size_t)i * 16 * EMBED);
            int gg = fcol >> 1, s8 = (fcol & 1) * 4;
            int idx = row * 64 + ((gg ^ (row & 7)) * 8) + s8;
            uint2 hv, lv;
            split2(v.x, v.y, hv.x, lv.x);
            split2(v.z, v.w, hv.y, lv.y);
            *(uint2*)(dh + idx) = hv;
            *(uint2*)(dl + idx) = lv;
        }
    }
    // ---- stage W: 64x64 fp32 -> hi/lo bf16, swizzled ----
    #pragma unroll
    for (int i = 0; i < 2; ++i) {
        int u = t + 256 * i;                  // granule 0..511
        int e = u >> 3, g = u & 7;
        const float* wb = Wp + u * 8;
        float4 v0 = *(const float4*)(wb);
        float4 v1 = *(const float4*)(wb + 4);
        uint4 hq, lq;
        split2(v0.x, v0.y, hq.x, lq.x);
        split2(v0.z, v0.w, hq.y, lq.y);
        split2(v1.x, v1.y, hq.z, lq.z);
        split2(v1.z, v1.w, hq.w, lq.w);
        int idx = e * 8 + (g ^ (e & 7));
        sWh[idx] = hq;
        sWl[idx] = lq;
    }
    __syncthreads();

    // ---- MFMA: per wave, 32-token tile x (two 32-wide e-tiles) ----
    f32x16 acc0, acc1;
    #pragma unroll
    for (int i = 0; i < 16; ++i) { acc0[i] = 0.f; acc1[i] = 0.f; }

    const int xrow = w * 32 + l5;
    const int w0r = l5, w1r = 32 + l5;
    #pragma unroll
    for (int kc = 0; kc < 4; ++kc) {
        int gsel = kc * 2 + hi;
        bf16x8 xh = as_bf16x8(sXh[xrow * 8 + (gsel ^ (xrow & 7))]);
        bf16x8 xl = as_bf16x8(sXl[xrow * 8 + (gsel ^ (xrow & 7))]);
        bf16x8 wh0 = as_bf16x8(sWh[w0r * 8 + (gsel ^ (w0r & 7))]);
        bf16x8 wl0 = as_bf16x8(sWl[w0r * 8 + (gsel ^ (w0r & 7))]);
        bf16x8 wh1 = as_bf16x8(sWh[w1r * 8 + (gsel ^ (w1r & 7))]);
        bf16x8 wl1 = as_bf16x8(sWl[w1r * 8 + (gsel ^ (w1r & 7))]);
        if (p == 0) {
            // V^T = W X^T : A=W-frag (rows e), B=X-frag (cols token)
            acc0 = __builtin_amdgcn_mfma_f32_32x32x16_bf16(wh0, xh, acc0, 0, 0, 0);
            acc0 = __builtin_amdgcn_mfma_f32_32x32x16_bf16(wh0, xl, acc0, 0, 0, 0);
            acc0 = __builtin_amdgcn_mfma_f32_32x32x16_bf16(wl0, xh, acc0, 0, 0, 0);
            acc1 = __builtin_amdgcn_mfma_f32_32x32x16_bf16(wh1, xh, acc1, 0, 0, 0);
            acc1 = __builtin_amdgcn_mfma_f32_32x32x16_bf16(wh1, xl, acc1, 0, 0, 0);
            acc1 = __builtin_amdgcn_mfma_f32_32x32x16_bf16(wl1, xh, acc1, 0, 0, 0);
        } else {
            // C = X W^T : A=X-frag (rows token), B=W-frag (cols e)
            acc0 = __builtin_amdgcn_mfma_f32_32x32x16_bf16(xh, wh0, acc0, 0, 0, 0);
            acc0 = __builtin_amdgcn_mfma_f32_32x32x16_bf16(xh, wl0, acc0, 0, 0, 0);
            acc0 = __builtin_amdgcn_mfma_f32_32x32x16_bf16(xl, wh0, acc0, 0, 0, 0);
            acc1 = __builtin_amdgcn_mfma_f32_32x32x16_bf16(xh, wh1, acc1, 0, 0, 0);
            acc1 = __builtin_amdgcn_mfma_f32_32x32x16_bf16(xh, wl1, acc1, 0, 0, 0);
            acc1 = __builtin_amdgcn_mfma_f32_32x32x16_bf16(xl, wh1, acc1, 0, 0, 0);
        }
    }

    // ---- epilogue ----
    if (p == 0) {
        // C rows = e, cols = token (V^T): coalesced Vt [N,H,D,L] stores
        unsigned short* vb = Vt + (((size_t)(n * HEADS + h)) * HD) * LSEQ + l0 + w * 32 + l5;
        #pragma unroll
        for (int r = 0; r < 16; ++r) {
            int er = (r & 3) + 8 * (r >> 2) + 4 * hi;
            vb[(size_t)er * LSEQ]        = bf16r(acc0[r]);
            vb[(size_t)(32 + er) * LSEQ] = bf16r(acc1[r]);
        }
    } else {
        unsigned short* dst = (p == 1) ? Kp : Qp;
        float sc = (p == 2) ? QSC : 1.0f;
        unsigned short* db = dst + (((size_t)(n * HEADS + h)) * LSEQ + l0 + w * 32) * HD;
        #pragma unroll
        for (int r = 0; r < 16; ++r) {
            int tok = (r & 3) + 8 * (r >> 2) + 4 * hi;
            db[(size_t)tok * HD + l5]      = bf16r(acc0[r] * sc);
            db[(size_t)tok * HD + 32 + l5] = bf16r(acc1[r] * sc);
        }
    }
}

// ---------------------------------------------------------------------------
// Kernel 2: MFMA flash attention, S^T orientation — unchanged (R8 form).
// ---------------------------------------------------------------------------
__global__ __launch_bounds__(256, 4) void attn_kernel(
    const unsigned short* __restrict__ Qp, const unsigned short* __restrict__ Kp,
    const unsigned short* __restrict__ Vt,
    unsigned short* __restrict__ AOh, unsigned short* __restrict__ AOl)
{
    __shared__ uint4 sK[2][64 * 8];  // [buf][key][granule]  8KB each
    __shared__ uint4 sV[2][64 * 8];  // [buf][d][key-granule] 8KB each

    const int t = threadIdx.x;
    const int lane = t & 63, w = t >> 6;
    const int l5 = lane & 31, hi = lane >> 5;
    const int n = blockIdx.z, h = blockIdx.y;
    const int q0 = blockIdx.x * 128;
    const size_t hoff = ((size_t)n * HEADS + h) * (size_t)(LSEQ * HD);
    const unsigned short* Kh = Kp + hoff;
    const unsigned short* Vh = Vt + hoff;

    bf16x8 qf[4];
    {
        const uint4* qg = (const uint4*)(Qp + hoff + (size_t)(q0 + w * 32 + l5) * HD);
        #pragma unroll
        for (int kc = 0; kc < 4; ++kc) qf[kc] = as_bf16x8(qg[kc * 2 + hi]);
    }

    f32x16 Oa0, Oa1;
    #pragma unroll
    for (int i = 0; i < 16; ++i) { Oa0[i] = 0.f; Oa1[i] = 0.f; }
    float ls0 = 0.f, ls1 = 0.f;

    const int r0 = t >> 3;                       // key-row / d-row 0..31
    const int g0 = (t & 7) ^ (r0 & 7);           // swizzled granule
    const uint4* gK = (const uint4*)Kh;
    const uint4* gV = (const uint4*)Vh;          // V^T: 256 uint4 per d-row

    #define STAGE(TILE, BUF)                                                        \
        do {                                                                        \
            int kb_ = (TILE) * 64;                                                  \
            gload_lds16(gK + (size_t)(kb_ + r0) * 8 + g0,        &sK[BUF][t]);      \
            gload_lds16(gK + (size_t)(kb_ + r0 + 32) * 8 + g0,   &sK[BUF][t + 256]);\
            gload_lds16(gV + (size_t)r0 * 256 + (kb_ >> 3) + g0, &sV[BUF][t]);      \
            gload_lds16(gV + (size_t)(r0 + 32) * 256 + (kb_ >> 3) + g0,             \
                        &sV[BUF][t + 256]);                                         \
        } while (0)

    STAGE(0, 0);
    int cur = 0;

    for (int tt = 0; tt < LSEQ / 64; ++tt) {
        if (tt + 1 < LSEQ / 64) {
            STAGE(tt + 1, cur ^ 1);
            asm volatile("s_waitcnt vmcnt(4)" ::: "memory");
        } else {
            asm volatile("s_waitcnt vmcnt(0)" ::: "memory");
        }
        __builtin_amdgcn_s_barrier();

        #pragma unroll
        for (int tc = 0; tc < 2; ++tc) {
            f32x16 c;
            #pragma unroll
            for (int i = 0; i < 16; ++i) c[i] = 0.f;
            int key = tc * 32 + l5;
            __builtin_amdgcn_s_setprio(1);
            #pragma unroll
            for (int kc = 0; kc < 4; ++kc) {
                bf16x8 kf = as_bf16x8(sK[cur][key * 8 + ((kc * 2 + hi) ^ (l5 & 7))]);
                c = __builtin_amdgcn_mfma_f32_32x32x16_bf16(kf, qf[kc], c, 0, 0, 0);
            }
            __builtin_amdgcn_s_setprio(0);

            unsigned pw[8];
            #pragma unroll
            for (int g = 0; g < 4; ++g) {
                float p0 = exp2f(c[4 * g]);
                float p1 = exp2f(c[4 * g + 1]);
                float p2 = exp2f(c[4 * g + 2]);
                float p3 = exp2f(c[4 * g + 3]);
                ls0 += (p0 + p1);
                ls1 += (p2 + p3);
                asm("v_cvt_pk_bf16_f32 %0, %1, %2" : "=v"(pw[2 * g])     : "v"(p0), "v"(p1));
                asm("v_cvt_pk_bf16_f32 %0, %1, %2" : "=v"(pw[2 * g + 1]) : "v"(p2), "v"(p3));
            }
            asm("v_permlane32_swap_b32 %0, %1" : "+v"(pw[0]), "+v"(pw[2]));
            asm("v_permlane32_swap_b32 %0, %1" : "+v"(pw[1]), "+v"(pw[3]));
            asm("v_permlane32_swap_b32 %0, %1" : "+v"(pw[4]), "+v"(pw[6]));
            asm("v_permlane32_swap_b32 %0, %1" : "+v"(pw[5]), "+v"(pw[7]));

            __builtin_amdgcn_s_setprio(1);
            #pragma unroll
            for (int win = 0; win < 2; ++win) {
                union { unsigned u[4]; bf16x8 b; } pf;
                pf.u[0] = pw[4 * win];
                pf.u[1] = pw[4 * win + 1];
                pf.u[2] = pw[4 * win + 2];
                pf.u[3] = pw[4 * win + 3];
                int vg = tc * 4 + (win << 1) + hi;
                bf16x8 v0 = as_bf16x8(sV[cur][ l5       * 8 + (vg ^ (l5 & 7))]);
                Oa0 = __builtin_amdgcn_mfma_f32_32x32x16_bf16(pf.b, v0, Oa0, 0, 0, 0);
                bf16x8 v1 = as_bf16x8(sV[cur][(32 + l5) * 8 + (vg ^ (l5 & 7))]);
                Oa1 = __builtin_amdgcn_mfma_f32_32x32x16_bf16(pf.b, v1, Oa1, 0, 0, 0);
            }
            __builtin_amdgcn_s_setprio(0);
        }
        __builtin_amdgcn_s_barrier();
        cur ^= 1;
    }
    #undef STAGE

    float lsum = ls0 + ls1;
    lsum += __shfl_xor(lsum, 32);
    float inv = 1.0f / lsum;
    float* sLf = (float*)&sK[0][0];
    if (hi == 0) sLf[w * 32 + l5] = inv;
    __syncthreads();

    unsigned short* hB = AOh + hoff;
    unsigned short* lB = AOl + hoff;
    #pragma unroll
    for (int r = 0; r < 16; ++r) {
        int qr = (r & 3) + 8 * (r >> 2) + 4 * hi;
        float invq = sLf[w * 32 + qr];
        size_t row = (size_t)(q0 + w * 32 + qr) * HD;
        float o0 = Oa0[r] * invq;
        float o1 = Oa1[r] * invq;
        unsigned short h0 = bf16r(o0), h1 = bf16r(o1);
        hB[row +      l5] = h0;
        hB[row + 32 + l5] = h1;
        lB[row +      l5] = bf16r(o0 - bfh2f(h0));
        lB[row + 32 + l5] = bf16r(o1 - bfh2f(h1));
    }
}

// ---------------------------------------------------------------------------
// Kernel 2.5: split Wo into bf16 hi/lo (unchanged).
// ---------------------------------------------------------------------------
__global__ __launch_bounds__(256) void wsplit_kernel(
    const float* __restrict__ Wo,
    unsigned short* __restrict__ Woh, unsigned short* __restrict__ Wol)
{
    int i = blockIdx.x * 256 + threadIdx.x;
    float4 v = ((const float4*)Wo)[i];
    ushort4 h, l;
    h.x = bf16r(v.x); l.x = bf16r(v.x - bfh2f(h.x));
    h.y = bf16r(v.y); l.y = bf16r(v.y - bfh2f(h.y));
    h.z = bf16r(v.z); l.z = bf16r(v.z - bfh2f(h.z));
    h.w = bf16r(v.w); l.w = bf16r(v.w - bfh2f(h.w));
    ((ushort4*)Woh)[i] = h;
    ((ushort4*)Wol)[i] = l;
}

// ---------------------------------------------------------------------------
// Kernel 3: output projection, split-bf16 MFMA GEMM.
// R11 change: e-tile halved 128 -> 64 (grid 512 -> 1024 blocks); per-chunk
// LDS footprint 32 -> 24KB, double-buffered = 48KB -> 3 blocks/CU (was 2).
// The 32-chunk barrier loop was latency-starved at 2 blocks/CU (1-deep
// prefetch covers ~400cy of the ~900cy HBM A-stream); more resident blocks
// cover the gap with TLP.  6 loads/chunk -> counted vmcnt(6).
// ---------------------------------------------------------------------------
__global__ __launch_bounds__(256, 3) void outproj_kernel(
    const unsigned short* __restrict__ AOh, const unsigned short* __restrict__ AOl,
    const unsigned short* __restrict__ Woh, const unsigned short* __restrict__ Wol,
    const float* __restrict__ bo, float* __restrict__ out)
{
    __shared__ uint4 sAh[2][512];   // [buf][arow*4 + g]  8KB each
    __shared__ uint4 sAl[2][512];
    __shared__ uint4 sBh[2][256];   // [buf][erow*4 + g]  4KB each
    __shared__ uint4 sBl[2][256];   // total 48KB

    const int t = threadIdx.x;
    const int lane = t & 63, w = t >> 6;
    const int l5 = lane & 31, hi = lane >> 5;
    const int m0 = blockIdx.x * 128;
    const int e0 = blockIdx.y * 64;
    const int n  = m0 >> 11, l0 = m0 & 2047;

    // staging: A slots t (row t>>2) and t+256 (row 64+(t>>2)); B slot t.
    // slot (row,g) holds source granule g ^ (row&3); (row+64)&3 == row&3.
    const int arow = t >> 2;
    const int aswz = (t & 3) ^ (arow & 3);

    #define OSTAGE(C, BUF)                                                            \
        do {                                                                          \
            int hh_ = (C) >> 1, hf_ = (C) & 1;                                        \
            const uint4* gAh_ = (const uint4*)(AOh) +                                 \
                (((size_t)n * HEADS + hh_) * LSEQ + l0) * 8 + hf_ * 4;                \
            const uint4* gAl_ = (const uint4*)(AOl) +                                 \
                (((size_t)n * HEADS + hh_) * LSEQ + l0) * 8 + hf_ * 4;                \
            const uint4* gBh_ = (const uint4*)(Woh) +                                 \
                (size_t)(e0 + arow) * 128 + hh_ * 8 + hf_ * 4;                        \
            const uint4* gBl_ = (const uint4*)(Wol) +                                 \
                (size_t)(e0 + arow) * 128 + hh_ * 8 + hf_ * 4;                        \
            gload_lds16(gAh_ + (size_t)arow * 8 + aswz,        &sAh[BUF][t]);         \
            gload_lds16(gAh_ + (size_t)(arow + 64) * 8 + aswz, &sAh[BUF][t + 256]);   \
            gload_lds16(gAl_ + (size_t)arow * 8 + aswz,        &sAl[BUF][t]);         \
            gload_lds16(gAl_ + (size_t)(arow + 64) * 8 + aswz, &sAl[BUF][t + 256]);   \
            gload_lds16(gBh_ + aswz, &sBh[BUF][t]);                                   \
            gload_lds16(gBl_ + aswz, &sBl[BUF][t]);                                   \
        } while (0)

    f32x16 acc0, acc1;
    #pragma unroll
    for (int i = 0; i < 16; ++i) { acc0[i] = 0.f; acc1[i] = 0.f; }

    OSTAGE(0, 0);
    int cur = 0;

    const int amr = w * 32 + l5;                 // A fragment row (token)
    for (int c = 0; c < 32; ++c) {
        if (c + 1 < 32) {
            OSTAGE(c + 1, cur ^ 1);
            asm volatile("s_waitcnt vmcnt(6)" ::: "memory");
        } else {
            asm volatile("s_waitcnt vmcnt(0)" ::: "memory");
        }
        __builtin_amdgcn_s_barrier();

        __builtin_amdgcn_s_setprio(1);
        #pragma unroll
        for (int ks = 0; ks < 2; ++ks) {
            int gx = ks * 2 + hi;
            bf16x8 ah = as_bf16x8(sAh[cur][amr * 4 + (gx ^ (amr & 3))]);
            bf16x8 al = as_bf16x8(sAl[cur][amr * 4 + (gx ^ (amr & 3))]);
            bf16x8 bh0 = as_bf16x8(sBh[cur][ l5       * 4 + (gx ^ (l5 & 3))]);
            bf16x8 bh1 = as_bf16x8(sBh[cur][(32 + l5) * 4 + (gx ^ (l5 & 3))]);
            bf16x8 bl0 = as_bf16x8(sBl[cur][ l5       * 4 + (gx ^ (l5 & 3))]);
            bf16x8 bl1 = as_bf16x8(sBl[cur][(32 + l5) * 4 + (gx ^ (l5 & 3))]);

            acc0 = __builtin_amdgcn_mfma_f32_32x32x16_bf16(ah, bh0, acc0, 0, 0, 0);
            acc1 = __builtin_amdgcn_mfma_f32_32x32x16_bf16(ah, bh1, acc1, 0, 0, 0);
            acc0 = __builtin_amdgcn_mfma_f32_32x32x16_bf16(ah, bl0, acc0, 0, 0, 0);
            acc1 = __builtin_amdgcn_mfma_f32_32x32x16_bf16(ah, bl1, acc1, 0, 0, 0);
            acc0 = __builtin_amdgcn_mfma_f32_32x32x16_bf16(al, bh0, acc0, 0, 0, 0);
            acc1 = __builtin_amdgcn_mfma_f32_32x32x16_bf16(al, bh1, acc1, 0, 0, 0);
        }
        __builtin_amdgcn_s_setprio(0);
        __builtin_amdgcn_s_barrier();
        cur ^= 1;
    }
    #undef OSTAGE

    float b0 = bo[e0 + l5];
    float b1 = bo[e0 + 32 + l5];
    #pragma unroll
    for (int r = 0; r < 16; ++r) {
        int row = m0 + w * 32 + (r & 3) + 8 * (r >> 2) + 4 * hi;
        float* o = out + (size_t)row * EMBED + e0;
        o[l5]      = acc0[r] + b0;
        o[32 + l5] = acc1[r] + b1;
    }
}

// ---------------------------------------------------------------------------
extern "C" void kernel_launch(void* const* d_in, const int* in_sizes, int n_in,
                              void* d_out, int out_size, void* d_ws, size_t ws_size,
                              hipStream_t stream)
{
    const float* values  = (const float*)d_in[0];
    const float* keys    = (const float*)d_in[1];
    const float* queries = (const float*)d_in[2];
    const float* Wv      = (const float*)d_in[3];
    const float* Wk      = (const float*)d_in[4];
    const float* Wq      = (const float*)d_in[5];
    const float* Wo      = (const float*)d_in[6];
    const float* bo      = (const float*)d_in[7];
    float* out = (float*)d_out;

    const size_t bufElems = (size_t)NB * HEADS * LSEQ * HD;   // 8,388,608
    unsigned short* Qp  = (unsigned short*)d_ws;
    unsigned short* Kp  = Qp  + bufElems;
    unsigned short* Vt  = Kp  + bufElems;
    unsigned short* AOh = Vt  + bufElems;
    unsigned short* AOl = AOh + bufElems;
    unsigned short* Woh = AOl + bufElems;
    unsigned short* Wol = Woh + (size_t)EMBED * EMBED;

    wsplit_kernel<<<dim3(1024), 256, 0, stream>>>(Wo, Woh, Wol);
    proj_kernel<<<dim3(NB * 16, HEADS, 3), 256, 0, stream>>>(values, keys, queries, Wv, Wk, Wq, Vt, Kp, Qp);
    attn_kernel<<<dim3(LSEQ / 128, HEADS, NB), 256, 0, stream>>>(Qp, Kp, Vt, AOh, AOl);
    outproj_kernel<<<dim3(NB * LSEQ / 128, EMBED / 64), 256, 0, stream>>>(AOh, AOl, Woh, Wol, bo, out);
}

// Round 7
// 349.923 us; speedup vs baseline: 1.0940x; 1.0073x over previous
//
#include <hip/hip_runtime.h>
#include <math.h>

#define EMBED 1024
#define HEADS 16
#define HD    64
#define NB    4
#define LSEQ  2048

typedef __attribute__((ext_vector_type(8))) short bf16x8;
typedef __attribute__((ext_vector_type(16))) float f32x16;

typedef __attribute__((address_space(1))) void as1_void;
typedef __attribute__((address_space(3))) void as3_void;

__device__ __forceinline__ void gload_lds16(const void* g, void* l) {
    __builtin_amdgcn_global_load_lds((const as1_void*)g, (as3_void*)l, 16, 0, 0);
}

__device__ inline bf16x8 as_bf16x8(uint4 u) {
    union { uint4 u; bf16x8 b; } c; c.u = u; return c.b;
}
// round-to-nearest-even fp32 -> bf16 (raw ushort); finite inputs only
__device__ inline unsigned short bf16r(float x) {
    unsigned u = __float_as_uint(x);
    u += 0x7fffu + ((u >> 16) & 1u);
    return (unsigned short)(u >> 16);
}
__device__ inline float bfh2f(unsigned short h) {
    return __uint_as_float(((unsigned)h) << 16);
}
// split two floats into packed hi/lo bf16 words
__device__ inline void split2(float x, float y, unsigned& hw, unsigned& lw) {
    unsigned short hx = bf16r(x), hy = bf16r(y);
    unsigned short lx = bf16r(x - bfh2f(hx)), ly = bf16r(y - bfh2f(hy));
    hw = (unsigned)hx | ((unsigned)hy << 16);
    lw = (unsigned)lx | ((unsigned)ly << 16);
}

// ---------------------------------------------------------------------------
// Kernel 1: QKV projections as split-bf16 MFMA GEMM (R11 structure).
// R12: wsplit folded in as blockIdx.z == 3 (one fewer kernel launch).
// ---------------------------------------------------------------------------
__global__ __launch_bounds__(256, 3) void proj_kernel(
    const float* __restrict__ Xv, const float* __restrict__ Xk, const float* __restrict__ Xq,
    const float* __restrict__ Wv, const float* __restrict__ Wk, const float* __restrict__ Wq,
    const float* __restrict__ Wo,
    unsigned short* __restrict__ Vt, unsigned short* __restrict__ Kp, unsigned short* __restrict__ Qp,
    unsigned short* __restrict__ Woh, unsigned short* __restrict__ Wol)
{
    __shared__ uint4 sXh[128 * 8];   // [token][granule of 8 dims]  16KB
    __shared__ uint4 sXl[128 * 8];   // 16KB
    __shared__ uint4 sWh[64 * 8];    // [e][granule of 8 dims]       8KB
    __shared__ uint4 sWl[64 * 8];    //                              8KB

    const int t = threadIdx.x;

    // ---- z == 3: Wo hi/lo split (former wsplit_kernel) ----
    if (blockIdx.z == 3) {
        int w_id = blockIdx.x + blockIdx.y * 64;          // 0..1023
        int i = w_id * 256 + t;
        float4 v = ((const float4*)Wo)[i];
        ushort4 h4, l4;
        h4.x = bf16r(v.x); l4.x = bf16r(v.x - bfh2f(h4.x));
        h4.y = bf16r(v.y); l4.y = bf16r(v.y - bfh2f(h4.y));
        h4.z = bf16r(v.z); l4.z = bf16r(v.z - bfh2f(h4.z));
        h4.w = bf16r(v.w); l4.w = bf16r(v.w - bfh2f(h4.w));
        ((ushort4*)Woh)[i] = h4;
        ((ushort4*)Wol)[i] = l4;
        return;
    }

    const int lane = t & 63, w = t >> 6;
    const int l5 = lane & 31, hi = lane >> 5;
    const int h  = blockIdx.y;
    const int n  = blockIdx.x >> 4;
    const int l0 = (blockIdx.x & 15) * 128;
    const int p  = blockIdx.z;

    const float QSC = 1.44269504088896341f / 32.0f;
    const float* Xp = (p == 0) ? Xv : (p == 1) ? Xk : Xq;
    const float* Wp = (p == 0) ? Wv : (p == 1) ? Wk : Wq;

    const int frow = t >> 4;        // staging: row group 0..15
    const int fcol = t & 15;        // float4 index within 64-dim row

    // ---- stage X tile: 128 rows x 64 dims fp32 -> hi/lo bf16, swizzled ----
    {
        const float* xb = Xp + ((size_t)(n * LSEQ + l0 + frow)) * EMBED + h * HD + fcol * 4;
        unsigned short* dh = (unsigned short*)sXh;
        unsigned short* dl = (unsigned short*)sXl;
        #pragma unroll
        for (int i = 0; i < 8; ++i) {
            int row = frow + i * 16;
            float4 v = *(const float4*)(xb + (size_t)i * 16 * EMBED);
            int gg = fcol >> 1, s8 = (fcol & 1) * 4;
            int idx = row * 64 + ((gg ^ (row & 7)) * 8) + s8;
            uint2 hv, lv;
            split2(v.x, v.y, hv.x, lv.x);
            split2(v.z, v.w, hv.y, lv.y);
            *(uint2*)(dh + idx) = hv;
            *(uint2*)(dl + idx) = lv;
        }
    }
    // ---- stage W: 64x64 fp32 -> hi/lo bf16, swizzled ----
    #pragma unroll
    for (int i = 0; i < 2; ++i) {
        int u = t + 256 * i;                  // granule 0..511
        int e = u >> 3, g = u & 7;
        const float* wb = Wp + u * 8;
        float4 v0 = *(const float4*)(wb);
        float4 v1 = *(const float4*)(wb + 4);
        uint4 hq, lq;
        split2(v0.x, v0.y, hq.x, lq.x);
        split2(v0.z, v0.w, hq.y, lq.y);
        split2(v1.x, v1.y, hq.z, lq.z);
        split2(v1.z, v1.w, hq.w, lq.w);
        int idx = e * 8 + (g ^ (e & 7));
        sWh[idx] = hq;
        sWl[idx] = lq;
    }
    __syncthreads();

    // ---- MFMA: per wave, 32-token tile x (two 32-wide e-tiles) ----
    f32x16 acc0, acc1;
    #pragma unroll
    for (int i = 0; i < 16; ++i) { acc0[i] = 0.f; acc1[i] = 0.f; }

    const int xrow = w * 32 + l5;
    const int w0r = l5, w1r = 32 + l5;
    #pragma unroll
    for (int kc = 0; kc < 4; ++kc) {
        int gsel = kc * 2 + hi;
        bf16x8 xh = as_bf16x8(sXh[xrow * 8 + (gsel ^ (xrow & 7))]);
        bf16x8 xl = as_bf16x8(sXl[xrow * 8 + (gsel ^ (xrow & 7))]);
        bf16x8 wh0 = as_bf16x8(sWh[w0r * 8 + (gsel ^ (w0r & 7))]);
        bf16x8 wl0 = as_bf16x8(sWl[w0r * 8 + (gsel ^ (w0r & 7))]);
        bf16x8 wh1 = as_bf16x8(sWh[w1r * 8 + (gsel ^ (w1r & 7))]);
        bf16x8 wl1 = as_bf16x8(sWl[w1r * 8 + (gsel ^ (w1r & 7))]);
        if (p == 0) {
            // V^T = W X^T : A=W-frag (rows e), B=X-frag (cols token)
            acc0 = __builtin_amdgcn_mfma_f32_32x32x16_bf16(wh0, xh, acc0, 0, 0, 0);
            acc0 = __builtin_amdgcn_mfma_f32_32x32x16_bf16(wh0, xl, acc0, 0, 0, 0);
            acc0 = __builtin_amdgcn_mfma_f32_32x32x16_bf16(wl0, xh, acc0, 0, 0, 0);
            acc1 = __builtin_amdgcn_mfma_f32_32x32x16_bf16(wh1, xh, acc1, 0, 0, 0);
            acc1 = __builtin_amdgcn_mfma_f32_32x32x16_bf16(wh1, xl, acc1, 0, 0, 0);
            acc1 = __builtin_amdgcn_mfma_f32_32x32x16_bf16(wl1, xh, acc1, 0, 0, 0);
        } else {
            // C = X W^T : A=X-frag (rows token), B=W-frag (cols e)
            acc0 = __builtin_amdgcn_mfma_f32_32x32x16_bf16(xh, wh0, acc0, 0, 0, 0);
            acc0 = __builtin_amdgcn_mfma_f32_32x32x16_bf16(xh, wl0, acc0, 0, 0, 0);
            acc0 = __builtin_amdgcn_mfma_f32_32x32x16_bf16(xl, wh0, acc0, 0, 0, 0);
            acc1 = __builtin_amdgcn_mfma_f32_32x32x16_bf16(xh, wh1, acc1, 0, 0, 0);
            acc1 = __builtin_amdgcn_mfma_f32_32x32x16_bf16(xh, wl1, acc1, 0, 0, 0);
            acc1 = __builtin_amdgcn_mfma_f32_32x32x16_bf16(xl, wh1, acc1, 0, 0, 0);
        }
    }

    // ---- epilogue ----
    if (p == 0) {
        // C rows = e, cols = token (V^T): coalesced Vt [N,H,D,L] stores
        unsigned short* vb = Vt + (((size_t)(n * HEADS + h)) * HD) * LSEQ + l0 + w * 32 + l5;
        #pragma unroll
        for (int r = 0; r < 16; ++r) {
            int er = (r & 3) + 8 * (r >> 2) + 4 * hi;
            vb[(size_t)er * LSEQ]        = bf16r(acc0[r]);
            vb[(size_t)(32 + er) * LSEQ] = bf16r(acc1[r]);
        }
    } else {
        unsigned short* dst = (p == 1) ? Kp : Qp;
        float sc = (p == 2) ? QSC : 1.0f;
        unsigned short* db = dst + (((size_t)(n * HEADS + h)) * LSEQ + l0 + w * 32) * HD;
        #pragma unroll
        for (int r = 0; r < 16; ++r) {
            int tok = (r & 3) + 8 * (r >> 2) + 4 * hi;
            db[(size_t)tok * HD + l5]      = bf16r(acc0[r] * sc);
            db[(size_t)tok * HD + 32 + l5] = bf16r(acc1[r] * sc);
        }
    }
}

// ---------------------------------------------------------------------------
// Kernel 2: MFMA flash attention, S^T orientation (R8 inner structure).
// R12 change (T1): bijective XCD-aware block remap.  The 16 q-tile blocks
// of one (n,h) all re-read the same 512KB of K/V; default dispatch
// round-robins them across the 8 XCDs, so every XCD's L2 fetches its own
// copy (FETCH 139MB vs 48MB ideal) and K/V loads run at HBM-miss latency.
// Remap puts all 16 q-tiles of a group on ONE XCD (8 groups/XCD = 4MB K/V
// ~ L2 size) -> K/V L2-hits after first touch.  Assumes XCD = linear
// dispatch id % 8 (heuristic only -> perf, not correctness).
// ---------------------------------------------------------------------------
__global__ __launch_bounds__(256, 4) void attn_kernel(
    const unsigned short* __restrict__ Qp, const unsigned short* __restrict__ Kp,
    const unsigned short* __restrict__ Vt,
    unsigned short* __restrict__ AOh, unsigned short* __restrict__ AOl)
{
    __shared__ uint4 sK[2][64 * 8];  // [buf][key][granule]  8KB each
    __shared__ uint4 sV[2][64 * 8];  // [buf][d][key-granule] 8KB each

    const int t = threadIdx.x;
    const int lane = t & 63, w = t >> 6;
    const int l5 = lane & 31, hi = lane >> 5;

    // T1 remap: b -> (xcd, u); group = xcd*8 + (u>>4) owns q-tiles u&15.
    const int b   = blockIdx.x + blockIdx.y * 16 + blockIdx.z * 256;
    const int xcd = b & 7, u = b >> 3;
    const int grp = xcd * 8 + (u >> 4);
    const int n   = grp >> 4, h = grp & 15;
    const int q0  = (u & 15) * 128;

    const size_t hoff = ((size_t)n * HEADS + h) * (size_t)(LSEQ * HD);
    const unsigned short* Kh = Kp + hoff;
    const unsigned short* Vh = Vt + hoff;

    bf16x8 qf[4];
    {
        const uint4* qg = (const uint4*)(Qp + hoff + (size_t)(q0 + w * 32 + l5) * HD);
        #pragma unroll
        for (int kc = 0; kc < 4; ++kc) qf[kc] = as_bf16x8(qg[kc * 2 + hi]);
    }

    f32x16 Oa0, Oa1;
    #pragma unroll
    for (int i = 0; i < 16; ++i) { Oa0[i] = 0.f; Oa1[i] = 0.f; }
    float ls0 = 0.f, ls1 = 0.f;

    const int r0 = t >> 3;                       // key-row / d-row 0..31
    const int g0 = (t & 7) ^ (r0 & 7);           // swizzled granule
    const uint4* gK = (const uint4*)Kh;
    const uint4* gV = (const uint4*)Vh;          // V^T: 256 uint4 per d-row

    #define STAGE(TILE, BUF)                                                        \
        do {                                                                        \
            int kb_ = (TILE) * 64;                                                  \
            gload_lds16(gK + (size_t)(kb_ + r0) * 8 + g0,        &sK[BUF][t]);      \
            gload_lds16(gK + (size_t)(kb_ + r0 + 32) * 8 + g0,   &sK[BUF][t + 256]);\
            gload_lds16(gV + (size_t)r0 * 256 + (kb_ >> 3) + g0, &sV[BUF][t]);      \
            gload_lds16(gV + (size_t)(r0 + 32) * 256 + (kb_ >> 3) + g0,             \
                        &sV[BUF][t + 256]);                                         \
        } while (0)

    STAGE(0, 0);
    int cur = 0;

    for (int tt = 0; tt < LSEQ / 64; ++tt) {
        if (tt + 1 < LSEQ / 64) {
            STAGE(tt + 1, cur ^ 1);
            asm volatile("s_waitcnt vmcnt(4)" ::: "memory");
        } else {
            asm volatile("s_waitcnt vmcnt(0)" ::: "memory");
        }
        __builtin_amdgcn_s_barrier();

        #pragma unroll
        for (int tc = 0; tc < 2; ++tc) {
            f32x16 c;
            #pragma unroll
            for (int i = 0; i < 16; ++i) c[i] = 0.f;
            int key = tc * 32 + l5;
            __builtin_amdgcn_s_setprio(1);
            #pragma unroll
            for (int kc = 0; kc < 4; ++kc) {
                bf16x8 kf = as_bf16x8(sK[cur][key * 8 + ((kc * 2 + hi) ^ (l5 & 7))]);
                c = __builtin_amdgcn_mfma_f32_32x32x16_bf16(kf, qf[kc], c, 0, 0, 0);
            }
            __builtin_amdgcn_s_setprio(0);

            unsigned pw[8];
            #pragma unroll
            for (int g = 0; g < 4; ++g) {
                float p0 = exp2f(c[4 * g]);
                float p1 = exp2f(c[4 * g + 1]);
                float p2 = exp2f(c[4 * g + 2]);
                float p3 = exp2f(c[4 * g + 3]);
                ls0 += (p0 + p1);
                ls1 += (p2 + p3);
                asm("v_cvt_pk_bf16_f32 %0, %1, %2" : "=v"(pw[2 * g])     : "v"(p0), "v"(p1));
                asm("v_cvt_pk_bf16_f32 %0, %1, %2" : "=v"(pw[2 * g + 1]) : "v"(p2), "v"(p3));
            }
            asm("v_permlane32_swap_b32 %0, %1" : "+v"(pw[0]), "+v"(pw[2]));
            asm("v_permlane32_swap_b32 %0, %1" : "+v"(pw[1]), "+v"(pw[3]));
            asm("v_permlane32_swap_b32 %0, %1" : "+v"(pw[4]), "+v"(pw[6]));
            asm("v_permlane32_swap_b32 %0, %1" : "+v"(pw[5]), "+v"(pw[7]));

            __builtin_amdgcn_s_setprio(1);
            #pragma unroll
            for (int win = 0; win < 2; ++win) {
                union { unsigned u[4]; bf16x8 b; } pf;
                pf.u[0] = pw[4 * win];
                pf.u[1] = pw[4 * win + 1];
                pf.u[2] = pw[4 * win + 2];
                pf.u[3] = pw[4 * win + 3];
                int vg = tc * 4 + (win << 1) + hi;
                bf16x8 v0 = as_bf16x8(sV[cur][ l5       * 8 + (vg ^ (l5 & 7))]);
                Oa0 = __builtin_amdgcn_mfma_f32_32x32x16_bf16(pf.b, v0, Oa0, 0, 0, 0);
                bf16x8 v1 = as_bf16x8(sV[cur][(32 + l5) * 8 + (vg ^ (l5 & 7))]);
                Oa1 = __builtin_amdgcn_mfma_f32_32x32x16_bf16(pf.b, v1, Oa1, 0, 0, 0);
            }
            __builtin_amdgcn_s_setprio(0);
        }
        __builtin_amdgcn_s_barrier();
        cur ^= 1;
    }
    #undef STAGE

    float lsum = ls0 + ls1;
    lsum += __shfl_xor(lsum, 32);
    float inv = 1.0f / lsum;
    float* sLf = (float*)&sK[0][0];
    if (hi == 0) sLf[w * 32 + l5] = inv;
    __syncthreads();

    unsigned short* hB = AOh + hoff;
    unsigned short* lB = AOl + hoff;
    #pragma unroll
    for (int r = 0; r < 16; ++r) {
        int qr = (r & 3) + 8 * (r >> 2) + 4 * hi;
        float invq = sLf[w * 32 + qr];
        size_t row = (size_t)(q0 + w * 32 + qr) * HD;
        float o0 = Oa0[r] * invq;
        float o1 = Oa1[r] * invq;
        unsigned short h0 = bf16r(o0), h1 = bf16r(o1);
        hB[row +      l5] = h0;
        hB[row + 32 + l5] = h1;
        lB[row +      l5] = bf16r(o0 - bfh2f(h0));
        lB[row + 32 + l5] = bf16r(o1 - bfh2f(h1));
    }
}

// ---------------------------------------------------------------------------
// Kernel 3: output projection, split-bf16 MFMA GEMM (R11 structure).
// R12 change (T1): XCD-aware remap — the 16 e-tile blocks sharing one
// m-tile's 512KB A-slice land on one XCD (8 m-tiles/XCD = 4MB ~ L2).
// ---------------------------------------------------------------------------
__global__ __launch_bounds__(256, 3) void outproj_kernel(
    const unsigned short* __restrict__ AOh, const unsigned short* __restrict__ AOl,
    const unsigned short* __restrict__ Woh, const unsigned short* __restrict__ Wol,
    const float* __restrict__ bo, float* __restrict__ out)
{
    __shared__ uint4 sAh[2][512];   // [buf][arow*4 + g]  8KB each
    __shared__ uint4 sAl[2][512];
    __shared__ uint4 sBh[2][256];   // [buf][erow*4 + g]  4KB each
    __shared__ uint4 sBl[2][256];   // total 48KB

    const int t = threadIdx.x;
    const int lane = t & 63, w = t >> 6;
    const int l5 = lane & 31, hi = lane >> 5;

    // T1 remap: l -> (xcd, u); m-tile = xcd*8 + (u&7), e-tile = u>>3.
    const int bl  = blockIdx.x + blockIdx.y * 64;
    const int xcd = bl & 7, u = bl >> 3;
    const int m0  = (xcd * 8 + (u & 7)) * 128;
    const int e0  = (u >> 3) * 64;
    const int n   = m0 >> 11, l0 = m0 & 2047;

    // staging: A slots t (row t>>2) and t+256 (row 64+(t>>2)); B slot t.
    // slot (row,g) holds source granule g ^ (row&3); (row+64)&3 == row&3.
    const int arow = t >> 2;
    const int aswz = (t & 3) ^ (arow & 3);

    #define OSTAGE(C, BUF)                                                            \
        do {                                                                          \
            int hh_ = (C) >> 1, hf_ = (C) & 1;                                        \
            const uint4* gAh_ = (const uint4*)(AOh) +                                 \
                (((size_t)n * HEADS + hh_) * LSEQ + l0) * 8 + hf_ * 4;                \
            const uint4* gAl_ = (const uint4*)(AOl) +                                 \
                (((size_t)n * HEADS + hh_) * LSEQ + l0) * 8 + hf_ * 4;                \
            const uint4* gBh_ = (const uint4*)(Woh) +                                 \
                (size_t)(e0 + arow) * 128 + hh_ * 8 + hf_ * 4;                        \
            const uint4* gBl_ = (const uint4*)(Wol) +                                 \
                (size_t)(e0 + arow) * 128 + hh_ * 8 + hf_ * 4;                        \
            gload_lds16(gAh_ + (size_t)arow * 8 + aswz,        &sAh[BUF][t]);         \
            gload_lds16(gAh_ + (size_t)(arow + 64) * 8 + aswz, &sAh[BUF][t + 256]);   \
            gload_lds16(gAl_ + (size_t)arow * 8 + aswz,        &sAl[BUF][t]);         \
            gload_lds16(gAl_ + (size_t)(arow + 64) * 8 + aswz, &sAl[BUF][t + 256]);   \
            gload_lds16(gBh_ + aswz, &sBh[BUF][t]);                                   \
            gload_lds16(gBl_ + aswz, &sBl[BUF][t]);                                   \
        } while (0)

    f32x16 acc0, acc1;
    #pragma unroll
    for (int i = 0; i < 16; ++i) { acc0[i] = 0.f; acc1[i] = 0.f; }

    OSTAGE(0, 0);
    int cur = 0;

    const int amr = w * 32 + l5;                 // A fragment row (token)
    for (int c = 0; c < 32; ++c) {
        if (c + 1 < 32) {
            OSTAGE(c + 1, cur ^ 1);
            asm volatile("s_waitcnt vmcnt(6)" ::: "memory");
        } else {
            asm volatile("s_waitcnt vmcnt(0)" ::: "memory");
        }
        __builtin_amdgcn_s_barrier();

        __builtin_amdgcn_s_setprio(1);
        #pragma unroll
        for (int ks = 0; ks < 2; ++ks) {
            int gx = ks * 2 + hi;
            bf16x8 ah = as_bf16x8(sAh[cur][amr * 4 + (gx ^ (amr & 3))]);
            bf16x8 al = as_bf16x8(sAl[cur][amr * 4 + (gx ^ (amr & 3))]);
            bf16x8 bh0 = as_bf16x8(sBh[cur][ l5       * 4 + (gx ^ (l5 & 3))]);
            bf16x8 bh1 = as_bf16x8(sBh[cur][(32 + l5) * 4 + (gx ^ (l5 & 3))]);
            bf16x8 bl0 = as_bf16x8(sBl[cur][ l5       * 4 + (gx ^ (l5 & 3))]);
            bf16x8 bl1 = as_bf16x8(sBl[cur][(32 + l5) * 4 + (gx ^ (l5 & 3))]);

            acc0 = __builtin_amdgcn_mfma_f32_32x32x16_bf16(ah, bh0, acc0, 0, 0, 0);
            acc1 = __builtin_amdgcn_mfma_f32_32x32x16_bf16(ah, bh1, acc1, 0, 0, 0);
            acc0 = __builtin_amdgcn_mfma_f32_32x32x16_bf16(ah, bl0, acc0, 0, 0, 0);
            acc1 = __builtin_amdgcn_mfma_f32_32x32x16_bf16(ah, bl1, acc1, 0, 0, 0);
            acc0 = __builtin_amdgcn_mfma_f32_32x32x16_bf16(al, bh0, acc0, 0, 0, 0);
            acc1 = __builtin_amdgcn_mfma_f32_32x32x16_bf16(al, bh1, acc1, 0, 0, 0);
        }
        __builtin_amdgcn_s_setprio(0);
        __builtin_amdgcn_s_barrier();
        cur ^= 1;
    }
    #undef OSTAGE

    float b0 = bo[e0 + l5];
    float b1 = bo[e0 + 32 + l5];
    #pragma unroll
    for (int r = 0; r < 16; ++r) {
        int row = m0 + w * 32 + (r & 3) + 8 * (r >> 2) + 4 * hi;
        float* o = out + (size_t)row * EMBED + e0;
        o[l5]      = acc0[r] + b0;
        o[32 + l5] = acc1[r] + b1;
    }
}

// ---------------------------------------------------------------------------
extern "C" void kernel_launch(void* const* d_in, const int* in_sizes, int n_in,
                              void* d_out, int out_size, void* d_ws, size_t ws_size,
                              hipStream_t stream)
{
    const float* values  = (const float*)d_in[0];
    const float* keys    = (const float*)d_in[1];
    const float* queries = (const float*)d_in[2];
    const float* Wv      = (const float*)d_in[3];
    const float* Wk      = (const float*)d_in[4];
    const float* Wq      = (const float*)d_in[5];
    const float* Wo      = (const float*)d_in[6];
    const float* bo      = (const float*)d_in[7];
    float* out = (float*)d_out;

    const size_t bufElems = (size_t)NB * HEADS * LSEQ * HD;   // 8,388,608
    unsigned short* Qp  = (unsigned short*)d_ws;
    unsigned short* Kp  = Qp  + bufElems;
    unsigned short* Vt  = Kp  + bufElems;
    unsigned short* AOh = Vt  + bufElems;
    unsigned short* AOl = AOh + bufElems;
    unsigned short* Woh = AOl + bufElems;
    unsigned short* Wol = Woh + (size_t)EMBED * EMBED;

    proj_kernel<<<dim3(NB * 16, HEADS, 4), 256, 0, stream>>>(
        values, keys, queries, Wv, Wk, Wq, Wo, Vt, Kp, Qp, Woh, Wol);
    attn_kernel<<<dim3(LSEQ / 128, HEADS, NB), 256, 0, stream>>>(Qp, Kp, Vt, AOh, AOl);
    outproj_kernel<<<dim3(NB * LSEQ / 128, EMBED / 64), 256, 0, stream>>>(AOh, AOl, Woh, Wol, bo, out);
}

// Round 8
// 327.086 us; speedup vs baseline: 1.1703x; 1.0698x over previous
//
#include <hip/hip_runtime.h>
#include <math.h>

#define EMBED 1024
#define HEADS 16
#define HD    64
#define NB    4
#define LSEQ  2048

typedef __attribute__((ext_vector_type(8))) short bf16x8;
typedef __attribute__((ext_vector_type(16))) float f32x16;

typedef __attribute__((address_space(1))) void as1_void;
typedef __attribute__((address_space(3))) void as3_void;

#if __has_builtin(__builtin_amdgcn_exp2f)
#define EXP2(x) __builtin_amdgcn_exp2f(x)
#else
#define EXP2(x) exp2f(x)
#endif

__device__ __forceinline__ void gload_lds16(const void* g, void* l) {
    __builtin_amdgcn_global_load_lds((const as1_void*)g, (as3_void*)l, 16, 0, 0);
}

__device__ inline bf16x8 as_bf16x8(uint4 u) {
    union { uint4 u; bf16x8 b; } c; c.u = u; return c.b;
}
// round-to-nearest-even fp32 -> bf16 (raw ushort); finite inputs only
__device__ inline unsigned short bf16r(float x) {
    unsigned u = __float_as_uint(x);
    u += 0x7fffu + ((u >> 16) & 1u);
    return (unsigned short)(u >> 16);
}
__device__ inline float bfh2f(unsigned short h) {
    return __uint_as_float(((unsigned)h) << 16);
}
// split two floats into packed hi/lo bf16 words
__device__ inline void split2(float x, float y, unsigned& hw, unsigned& lw) {
    unsigned short hx = bf16r(x), hy = bf16r(y);
    unsigned short lx = bf16r(x - bfh2f(hx)), ly = bf16r(y - bfh2f(hy));
    hw = (unsigned)hx | ((unsigned)hy << 16);
    lw = (unsigned)lx | ((unsigned)ly << 16);
}

// ---------------------------------------------------------------------------
// Kernel 1: QKV projections as split-bf16 MFMA GEMM (R12 form, unchanged).
// ---------------------------------------------------------------------------
__global__ __launch_bounds__(256, 3) void proj_kernel(
    const float* __restrict__ Xv, const float* __restrict__ Xk, const float* __restrict__ Xq,
    const float* __restrict__ Wv, const float* __restrict__ Wk, const float* __restrict__ Wq,
    const float* __restrict__ Wo,
    unsigned short* __restrict__ Vt, unsigned short* __restrict__ Kp, unsigned short* __restrict__ Qp,
    unsigned short* __restrict__ Woh, unsigned short* __restrict__ Wol)
{
    __shared__ uint4 sXh[128 * 8];   // [token][granule of 8 dims]  16KB
    __shared__ uint4 sXl[128 * 8];   // 16KB
    __shared__ uint4 sWh[64 * 8];    // [e][granule of 8 dims]       8KB
    __shared__ uint4 sWl[64 * 8];    //                              8KB

    const int t = threadIdx.x;

    // ---- z == 3: Wo hi/lo split (former wsplit_kernel) ----
    if (blockIdx.z == 3) {
        int w_id = blockIdx.x + blockIdx.y * 64;          // 0..1023
        int i = w_id * 256 + t;
        float4 v = ((const float4*)Wo)[i];
        ushort4 h4, l4;
        h4.x = bf16r(v.x); l4.x = bf16r(v.x - bfh2f(h4.x));
        h4.y = bf16r(v.y); l4.y = bf16r(v.y - bfh2f(h4.y));
        h4.z = bf16r(v.z); l4.z = bf16r(v.z - bfh2f(h4.z));
        h4.w = bf16r(v.w); l4.w = bf16r(v.w - bfh2f(h4.w));
        ((ushort4*)Woh)[i] = h4;
        ((ushort4*)Wol)[i] = l4;
        return;
    }

    const int lane = t & 63, w = t >> 6;
    const int l5 = lane & 31, hi = lane >> 5;
    const int h  = blockIdx.y;
    const int n  = blockIdx.x >> 4;
    const int l0 = (blockIdx.x & 15) * 128;
    const int p  = blockIdx.z;

    const float QSC = 1.44269504088896341f / 32.0f;
    const float* Xp = (p == 0) ? Xv : (p == 1) ? Xk : Xq;
    const float* Wp = (p == 0) ? Wv : (p == 1) ? Wk : Wq;

    const int frow = t >> 4;        // staging: row group 0..15
    const int fcol = t & 15;        // float4 index within 64-dim row

    // ---- stage X tile: 128 rows x 64 dims fp32 -> hi/lo bf16, swizzled ----
    {
        const float* xb = Xp + ((size_t)(n * LSEQ + l0 + frow)) * EMBED + h * HD + fcol * 4;
        unsigned short* dh = (unsigned short*)sXh;
        unsigned short* dl = (unsigned short*)sXl;
        #pragma unroll
        for (int i = 0; i < 8; ++i) {
            int row = frow + i * 16;
            float4 v = *(const float4*)(xb + (size_t)i * 16 * EMBED);
            int gg = fcol >> 1, s8 = (fcol & 1) * 4;
            int idx = row * 64 + ((gg ^ (row & 7)) * 8) + s8;
            uint2 hv, lv;
            split2(v.x, v.y, hv.x, lv.x);
            split2(v.z, v.w, hv.y, lv.y);
            *(uint2*)(dh + idx) = hv;
            *(uint2*)(dl + idx) = lv;
        }
    }
    // ---- stage W: 64x64 fp32 -> hi/lo bf16, swizzled ----
    #pragma unroll
    for (int i = 0; i < 2; ++i) {
        int u = t + 256 * i;                  // granule 0..511
        int e = u >> 3, g = u & 7;
        const float* wb = Wp + u * 8;
        float4 v0 = *(const float4*)(wb);
        float4 v1 = *(const float4*)(wb + 4);
        uint4 hq, lq;
        split2(v0.x, v0.y, hq.x, lq.x);
        split2(v0.z, v0.w, hq.y, lq.y);
        split2(v1.x, v1.y, hq.z, lq.z);
        split2(v1.z, v1.w, hq.w, lq.w);
        int idx = e * 8 + (g ^ (e & 7));
        sWh[idx] = hq;
        sWl[idx] = lq;
    }
    __syncthreads();

    // ---- MFMA: per wave, 32-token tile x (two 32-wide e-tiles) ----
    f32x16 acc0, acc1;
    #pragma unroll
    for (int i = 0; i < 16; ++i) { acc0[i] = 0.f; acc1[i] = 0.f; }

    const int xrow = w * 32 + l5;
    const int w0r = l5, w1r = 32 + l5;
    #pragma unroll
    for (int kc = 0; kc < 4; ++kc) {
        int gsel = kc * 2 + hi;
        bf16x8 xh = as_bf16x8(sXh[xrow * 8 + (gsel ^ (xrow & 7))]);
        bf16x8 xl = as_bf16x8(sXl[xrow * 8 + (gsel ^ (xrow & 7))]);
        bf16x8 wh0 = as_bf16x8(sWh[w0r * 8 + (gsel ^ (w0r & 7))]);
        bf16x8 wl0 = as_bf16x8(sWl[w0r * 8 + (gsel ^ (w0r & 7))]);
        bf16x8 wh1 = as_bf16x8(sWh[w1r * 8 + (gsel ^ (w1r & 7))]);
        bf16x8 wl1 = as_bf16x8(sWl[w1r * 8 + (gsel ^ (w1r & 7))]);
        if (p == 0) {
            // V^T = W X^T : A=W-frag (rows e), B=X-frag (cols token)
            acc0 = __builtin_amdgcn_mfma_f32_32x32x16_bf16(wh0, xh, acc0, 0, 0, 0);
            acc0 = __builtin_amdgcn_mfma_f32_32x32x16_bf16(wh0, xl, acc0, 0, 0, 0);
            acc0 = __builtin_amdgcn_mfma_f32_32x32x16_bf16(wl0, xh, acc0, 0, 0, 0);
            acc1 = __builtin_amdgcn_mfma_f32_32x32x16_bf16(wh1, xh, acc1, 0, 0, 0);
            acc1 = __builtin_amdgcn_mfma_f32_32x32x16_bf16(wh1, xl, acc1, 0, 0, 0);
            acc1 = __builtin_amdgcn_mfma_f32_32x32x16_bf16(wl1, xh, acc1, 0, 0, 0);
        } else {
            // C = X W^T : A=X-frag (rows token), B=W-frag (cols e)
            acc0 = __builtin_amdgcn_mfma_f32_32x32x16_bf16(xh, wh0, acc0, 0, 0, 0);
            acc0 = __builtin_amdgcn_mfma_f32_32x32x16_bf16(xh, wl0, acc0, 0, 0, 0);
            acc0 = __builtin_amdgcn_mfma_f32_32x32x16_bf16(xl, wh0, acc0, 0, 0, 0);
            acc1 = __builtin_amdgcn_mfma_f32_32x32x16_bf16(xh, wh1, acc1, 0, 0, 0);
            acc1 = __builtin_amdgcn_mfma_f32_32x32x16_bf16(xh, wl1, acc1, 0, 0, 0);
            acc1 = __builtin_amdgcn_mfma_f32_32x32x16_bf16(xl, wh1, acc1, 0, 0, 0);
        }
    }

    // ---- epilogue ----
    if (p == 0) {
        // C rows = e, cols = token (V^T): coalesced Vt [N,H,D,L] stores
        unsigned short* vb = Vt + (((size_t)(n * HEADS + h)) * HD) * LSEQ + l0 + w * 32 + l5;
        #pragma unroll
        for (int r = 0; r < 16; ++r) {
            int er = (r & 3) + 8 * (r >> 2) + 4 * hi;
            vb[(size_t)er * LSEQ]        = bf16r(acc0[r]);
            vb[(size_t)(32 + er) * LSEQ] = bf16r(acc1[r]);
        }
    } else {
        unsigned short* dst = (p == 1) ? Kp : Qp;
        float sc = (p == 2) ? QSC : 1.0f;
        unsigned short* db = dst + (((size_t)(n * HEADS + h)) * LSEQ + l0 + w * 32) * HD;
        #pragma unroll
        for (int r = 0; r < 16; ++r) {
            int tok = (r & 3) + 8 * (r >> 2) + 4 * hi;
            db[(size_t)tok * HD + l5]      = bf16r(acc0[r] * sc);
            db[(size_t)tok * HD + 32 + l5] = bf16r(acc1[r] * sc);
        }
    }
}

// ---------------------------------------------------------------------------
// Kernel 2: MFMA flash attention, S^T orientation.
// R13 (attn is issue-bound: VALU 66% / MFMA 25% / HBM 6% after T1):
//  - zero-accumulator trick: persistent z16=0 tuple feeds C of the first
//    MFMA of each S-tile (D!=C allowed) -> deletes 16 zero-movs x 64 tiles
//    = 1024 insts/thread.
//  - tt unrolled by 2 with compile-time buffer index -> LDS addresses become
//    loop-invariant, no `cur` arithmetic.
//  - EXP2 builtin (guaranteed single v_exp_f32).
//  - P-words held in uint4 so cvt_pk/permlane outputs land in the MFMA
//    operand tuple without union copies.
// Schedule (STAGE/vmcnt(4)/barriers), T1 remap, setprio: unchanged from R12.
// ---------------------------------------------------------------------------
__global__ __launch_bounds__(256, 4) void attn_kernel(
    const unsigned short* __restrict__ Qp, const unsigned short* __restrict__ Kp,
    const unsigned short* __restrict__ Vt,
    unsigned short* __restrict__ AOh, unsigned short* __restrict__ AOl)
{
    __shared__ uint4 sK[2][64 * 8];  // [buf][key][granule]  8KB each
    __shared__ uint4 sV[2][64 * 8];  // [buf][d][key-granule] 8KB each

    const int t = threadIdx.x;
    const int lane = t & 63, w = t >> 6;
    const int l5 = lane & 31, hi = lane >> 5;

    // T1 remap: b -> (xcd, u); group = xcd*8 + (u>>4) owns q-tiles u&15.
    const int b   = blockIdx.x + blockIdx.y * 16 + blockIdx.z * 256;
    const int xcd = b & 7, u = b >> 3;
    const int grp = xcd * 8 + (u >> 4);
    const int n   = grp >> 4, h = grp & 15;
    const int q0  = (u & 15) * 128;

    const size_t hoff = ((size_t)n * HEADS + h) * (size_t)(LSEQ * HD);
    const unsigned short* Kh = Kp + hoff;
    const unsigned short* Vh = Vt + hoff;

    bf16x8 qf[4];
    {
        const uint4* qg = (const uint4*)(Qp + hoff + (size_t)(q0 + w * 32 + l5) * HD);
        #pragma unroll
        for (int kc = 0; kc < 4; ++kc) qf[kc] = as_bf16x8(qg[kc * 2 + hi]);
    }

    f32x16 z16;
    #pragma unroll
    for (int i = 0; i < 16; ++i) z16[i] = 0.f;
    f32x16 Oa0 = z16, Oa1 = z16;
    float ls0 = 0.f, ls1 = 0.f;

    const int r0 = t >> 3;                       // key-row / d-row 0..31
    const int g0 = (t & 7) ^ (r0 & 7);           // swizzled granule
    const uint4* gK = (const uint4*)Kh;
    const uint4* gV = (const uint4*)Vh;          // V^T: 256 uint4 per d-row

    #define STAGE(TILE, BUF)                                                        \
        do {                                                                        \
            int kb_ = (TILE) * 64;                                                  \
            gload_lds16(gK + (size_t)(kb_ + r0) * 8 + g0,        &sK[BUF][t]);      \
            gload_lds16(gK + (size_t)(kb_ + r0 + 32) * 8 + g0,   &sK[BUF][t + 256]);\
            gload_lds16(gV + (size_t)r0 * 256 + (kb_ >> 3) + g0, &sV[BUF][t]);      \
            gload_lds16(gV + (size_t)(r0 + 32) * 256 + (kb_ >> 3) + g0,             \
                        &sV[BUF][t + 256]);                                         \
        } while (0)

    #define COMPUTE(BUF)                                                            \
        do {                                                                        \
            _Pragma("unroll")                                                       \
            for (int tc = 0; tc < 2; ++tc) {                                        \
                int key = tc * 32 + l5;                                             \
                __builtin_amdgcn_s_setprio(1);                                      \
                bf16x8 kf0 = as_bf16x8(sK[BUF][key * 8 + (hi ^ (l5 & 7))]);         \
                f32x16 c = __builtin_amdgcn_mfma_f32_32x32x16_bf16(kf0, qf[0], z16, 0, 0, 0); \
                _Pragma("unroll")                                                   \
                for (int kc = 1; kc < 4; ++kc) {                                    \
                    bf16x8 kf = as_bf16x8(sK[BUF][key * 8 + ((kc * 2 + hi) ^ (l5 & 7))]); \
                    c = __builtin_amdgcn_mfma_f32_32x32x16_bf16(kf, qf[kc], c, 0, 0, 0);  \
                }                                                                   \
                __builtin_amdgcn_s_setprio(0);                                      \
                uint4 pwa, pwb;                                                     \
                {                                                                   \
                    float p0 = EXP2(c[0]),  p1 = EXP2(c[1]);                        \
                    float p2 = EXP2(c[2]),  p3 = EXP2(c[3]);                        \
                    ls0 += p0 + p1; ls1 += p2 + p3;                                 \
                    asm("v_cvt_pk_bf16_f32 %0, %1, %2" : "=v"(pwa.x) : "v"(p0), "v"(p1)); \
                    asm("v_cvt_pk_bf16_f32 %0, %1, %2" : "=v"(pwa.y) : "v"(p2), "v"(p3)); \
                    p0 = EXP2(c[4]);  p1 = EXP2(c[5]);                              \
                    p2 = EXP2(c[6]);  p3 = EXP2(c[7]);                              \
                    ls0 += p0 + p1; ls1 += p2 + p3;                                 \
                    asm("v_cvt_pk_bf16_f32 %0, %1, %2" : "=v"(pwa.z) : "v"(p0), "v"(p1)); \
                    asm("v_cvt_pk_bf16_f32 %0, %1, %2" : "=v"(pwa.w) : "v"(p2), "v"(p3)); \
                    p0 = EXP2(c[8]);  p1 = EXP2(c[9]);                              \
                    p2 = EXP2(c[10]); p3 = EXP2(c[11]);                             \
                    ls0 += p0 + p1; ls1 += p2 + p3;                                 \
                    asm("v_cvt_pk_bf16_f32 %0, %1, %2" : "=v"(pwb.x) : "v"(p0), "v"(p1)); \
                    asm("v_cvt_pk_bf16_f32 %0, %1, %2" : "=v"(pwb.y) : "v"(p2), "v"(p3)); \
                    p0 = EXP2(c[12]); p1 = EXP2(c[13]);                             \
                    p2 = EXP2(c[14]); p3 = EXP2(c[15]);                             \
                    ls0 += p0 + p1; ls1 += p2 + p3;                                 \
                    asm("v_cvt_pk_bf16_f32 %0, %1, %2" : "=v"(pwb.z) : "v"(p0), "v"(p1)); \
                    asm("v_cvt_pk_bf16_f32 %0, %1, %2" : "=v"(pwb.w) : "v"(p2), "v"(p3)); \
                }                                                                   \
                asm("v_permlane32_swap_b32 %0, %1" : "+v"(pwa.x), "+v"(pwa.z));     \
                asm("v_permlane32_swap_b32 %0, %1" : "+v"(pwa.y), "+v"(pwa.w));     \
                asm("v_permlane32_swap_b32 %0, %1" : "+v"(pwb.x), "+v"(pwb.z));     \
                asm("v_permlane32_swap_b32 %0, %1" : "+v"(pwb.y), "+v"(pwb.w));     \
                __builtin_amdgcn_s_setprio(1);                                      \
                {                                                                   \
                    int vg0 = tc * 4 + hi;                                          \
                    bf16x8 pa = as_bf16x8(pwa);                                     \
                    bf16x8 v0 = as_bf16x8(sV[BUF][ l5       * 8 + (vg0 ^ (l5 & 7))]); \
                    Oa0 = __builtin_amdgcn_mfma_f32_32x32x16_bf16(pa, v0, Oa0, 0, 0, 0); \
                    bf16x8 v1 = as_bf16x8(sV[BUF][(32 + l5) * 8 + (vg0 ^ (l5 & 7))]); \
                    Oa1 = __builtin_amdgcn_mfma_f32_32x32x16_bf16(pa, v1, Oa1, 0, 0, 0); \
                    int vg1 = tc * 4 + 2 + hi;                                      \
                    bf16x8 pb = as_bf16x8(pwb);                                     \
                    bf16x8 v2 = as_bf16x8(sV[BUF][ l5       * 8 + (vg1 ^ (l5 & 7))]); \
                    Oa0 = __builtin_amdgcn_mfma_f32_32x32x16_bf16(pb, v2, Oa0, 0, 0, 0); \
                    bf16x8 v3 = as_bf16x8(sV[BUF][(32 + l5) * 8 + (vg1 ^ (l5 & 7))]); \
                    Oa1 = __builtin_amdgcn_mfma_f32_32x32x16_bf16(pb, v3, Oa1, 0, 0, 0); \
                }                                                                   \
                __builtin_amdgcn_s_setprio(0);                                      \
            }                                                                       \
        } while (0)

    STAGE(0, 0);

    for (int tt = 0; tt < LSEQ / 64; tt += 2) {
        STAGE(tt + 1, 1);
        asm volatile("s_waitcnt vmcnt(4)" ::: "memory");
        __builtin_amdgcn_s_barrier();
        COMPUTE(0);
        __builtin_amdgcn_s_barrier();

        if (tt + 2 < LSEQ / 64) {
            STAGE(tt + 2, 0);
            asm volatile("s_waitcnt vmcnt(4)" ::: "memory");
        } else {
            asm volatile("s_waitcnt vmcnt(0)" ::: "memory");
        }
        __builtin_amdgcn_s_barrier();
        COMPUTE(1);
        __builtin_amdgcn_s_barrier();
    }
    #undef STAGE
    #undef COMPUTE

    float lsum = ls0 + ls1;
    lsum += __shfl_xor(lsum, 32);
    float inv = 1.0f / lsum;
    float* sLf = (float*)&sK[0][0];
    if (hi == 0) sLf[w * 32 + l5] = inv;
    __syncthreads();

    unsigned short* hB = AOh + hoff;
    unsigned short* lB = AOl + hoff;
    #pragma unroll
    for (int r = 0; r < 16; ++r) {
        int qr = (r & 3) + 8 * (r >> 2) + 4 * hi;
        float invq = sLf[w * 32 + qr];
        size_t row = (size_t)(q0 + w * 32 + qr) * HD;
        float o0 = Oa0[r] * invq;
        float o1 = Oa1[r] * invq;
        unsigned short h0 = bf16r(o0), h1 = bf16r(o1);
        hB[row +      l5] = h0;
        hB[row + 32 + l5] = h1;
        lB[row +      l5] = bf16r(o0 - bfh2f(h0));
        lB[row + 32 + l5] = bf16r(o1 - bfh2f(h1));
    }
}

// ---------------------------------------------------------------------------
// Kernel 3: output projection, split-bf16 MFMA GEMM (R12 form, unchanged).
// ---------------------------------------------------------------------------
__global__ __launch_bounds__(256, 3) void outproj_kernel(
    const unsigned short* __restrict__ AOh, const unsigned short* __restrict__ AOl,
    const unsigned short* __restrict__ Woh, const unsigned short* __restrict__ Wol,
    const float* __restrict__ bo, float* __restrict__ out)
{
    __shared__ uint4 sAh[2][512];   // [buf][arow*4 + g]  8KB each
    __shared__ uint4 sAl[2][512];
    __shared__ uint4 sBh[2][256];   // [buf][erow*4 + g]  4KB each
    __shared__ uint4 sBl[2][256];   // total 48KB

    const int t = threadIdx.x;
    const int lane = t & 63, w = t >> 6;
    const int l5 = lane & 31, hi = lane >> 5;

    // T1 remap: l -> (xcd, u); m-tile = xcd*8 + (u&7), e-tile = u>>3.
    const int bl  = blockIdx.x + blockIdx.y * 64;
    const int xcd = bl & 7, u = bl >> 3;
    const int m0  = (xcd * 8 + (u & 7)) * 128;
    const int e0  = (u >> 3) * 64;
    const int n   = m0 >> 11, l0 = m0 & 2047;

    // staging: A slots t (row t>>2) and t+256 (row 64+(t>>2)); B slot t.
    // slot (row,g) holds source granule g ^ (row&3); (row+64)&3 == row&3.
    const int arow = t >> 2;
    const int aswz = (t & 3) ^ (arow & 3);

    #define OSTAGE(C, BUF)                                                            \
        do {                                                                          \
            int hh_ = (C) >> 1, hf_ = (C) & 1;                                        \
            const uint4* gAh_ = (const uint4*)(AOh) +                                 \
                (((size_t)n * HEADS + hh_) * LSEQ + l0) * 8 + hf_ * 4;                \
            const uint4* gAl_ = (const uint4*)(AOl) +                                 \
                (((size_t)n * HEADS + hh_) * LSEQ + l0) * 8 + hf_ * 4;                \
            const uint4* gBh_ = (const uint4*)(Woh) +                                 \
                (size_t)(e0 + arow) * 128 + hh_ * 8 + hf_ * 4;                        \
            const uint4* gBl_ = (const uint4*)(Wol) +                                 \
                (size_t)(e0 + arow) * 128 + hh_ * 8 + hf_ * 4;                        \
            gload_lds16(gAh_ + (size_t)arow * 8 + aswz,        &sAh[BUF][t]);         \
            gload_lds16(gAh_ + (size_t)(arow + 64) * 8 + aswz, &sAh[BUF][t + 256]);   \
            gload_lds16(gAl_ + (size_t)arow * 8 + aswz,        &sAl[BUF][t]);         \
            gload_lds16(gAl_ + (size_t)(arow + 64) * 8 + aswz, &sAl[BUF][t + 256]);   \
            gload_lds16(gBh_ + aswz, &sBh[BUF][t]);                                   \
            gload_lds16(gBl_ + aswz, &sBl[BUF][t]);                                   \
        } while (0)

    f32x16 acc0, acc1;
    #pragma unroll
    for (int i = 0; i < 16; ++i) { acc0[i] = 0.f; acc1[i] = 0.f; }

    OSTAGE(0, 0);
    int cur = 0;

    const int amr = w * 32 + l5;                 // A fragment row (token)
    for (int c = 0; c < 32; ++c) {
        if (c + 1 < 32) {
            OSTAGE(c + 1, cur ^ 1);
            asm volatile("s_waitcnt vmcnt(6)" ::: "memory");
        } else {
            asm volatile("s_waitcnt vmcnt(0)" ::: "memory");
        }
        __builtin_amdgcn_s_barrier();

        __builtin_amdgcn_s_setprio(1);
        #pragma unroll
        for (int ks = 0; ks < 2; ++ks) {
            int gx = ks * 2 + hi;
            bf16x8 ah = as_bf16x8(sAh[cur][amr * 4 + (gx ^ (amr & 3))]);
            bf16x8 al = as_bf16x8(sAl[cur][amr * 4 + (gx ^ (amr & 3))]);
            bf16x8 bh0 = as_bf16x8(sBh[cur][ l5       * 4 + (gx ^ (l5 & 3))]);
            bf16x8 bh1 = as_bf16x8(sBh[cur][(32 + l5) * 4 + (gx ^ (l5 & 3))]);
            bf16x8 bl0 = as_bf16x8(sBl[cur][ l5       * 4 + (gx ^ (l5 & 3))]);
            bf16x8 bl1 = as_bf16x8(sBl[cur][(32 + l5) * 4 + (gx ^ (l5 & 3))]);

            acc0 = __builtin_amdgcn_mfma_f32_32x32x16_bf16(ah, bh0, acc0, 0, 0, 0);
            acc1 = __builtin_amdgcn_mfma_f32_32x32x16_bf16(ah, bh1, acc1, 0, 0, 0);
            acc0 = __builtin_amdgcn_mfma_f32_32x32x16_bf16(ah, bl0, acc0, 0, 0, 0);
            acc1 = __builtin_amdgcn_mfma_f32_32x32x16_bf16(ah, bl1, acc1, 0, 0, 0);
            acc0 = __builtin_amdgcn_mfma_f32_32x32x16_bf16(al, bh0, acc0, 0, 0, 0);
            acc1 = __builtin_amdgcn_mfma_f32_32x32x16_bf16(al, bh1, acc1, 0, 0, 0);
        }
        __builtin_amdgcn_s_setprio(0);
        __builtin_amdgcn_s_barrier();
        cur ^= 1;
    }
    #undef OSTAGE

    float b0 = bo[e0 + l5];
    float b1 = bo[e0 + 32 + l5];
    #pragma unroll
    for (int r = 0; r < 16; ++r) {
        int row = m0 + w * 32 + (r & 3) + 8 * (r >> 2) + 4 * hi;
        float* o = out + (size_t)row * EMBED + e0;
        o[l5]      = acc0[r] + b0;
        o[32 + l5] = acc1[r] + b1;
    }
}

// ---------------------------------------------------------------------------
extern "C" void kernel_launch(void* const* d_in, const int* in_sizes, int n_in,
                              void* d_out, int out_size, void* d_ws, size_t ws_size,
                              hipStream_t stream)
{
    const float* values  = (const float*)d_in[0];
    const float* keys    = (const float*)d_in[1];
    const float* queries = (const float*)d_in[2];
    const float* Wv      = (const float*)d_in[3];
    const float* Wk      = (const float*)d_in[4];
    const float* Wq      = (const float*)d_in[5];
    const float* Wo      = (const float*)d_in[6];
    const float* bo      = (const float*)d_in[7];
    float* out = (float*)d_out;

    const size_t bufElems = (size_t)NB * HEADS * LSEQ * HD;   // 8,388,608
    unsigned short* Qp  = (unsigned short*)d_ws;
    unsigned short* Kp  = Qp  + bufElems;
    unsigned short* Vt  = Kp  + bufElems;
    unsigned short* AOh = Vt  + bufElems;
    unsigned short* AOl = AOh + bufElems;
    unsigned short* Woh = AOl + bufElems;
    unsigned short* Wol = Woh + (size_t)EMBED * EMBED;

    proj_kernel<<<dim3(NB * 16, HEADS, 4), 256, 0, stream>>>(
        values, keys, queries, Wv, Wk, Wq, Wo, Vt, Kp, Qp, Woh, Wol);
    attn_kernel<<<dim3(LSEQ / 128, HEADS, NB), 256, 0, stream>>>(Qp, Kp, Vt, AOh, AOl);
    outproj_kernel<<<dim3(NB * LSEQ / 128, EMBED / 64), 256, 0, stream>>>(AOh, AOl, Woh, Wol, bo, out);
}

// Round 9
// 319.396 us; speedup vs baseline: 1.1985x; 1.0241x over previous
//
#include <hip/hip_runtime.h>
#include <math.h>

#define EMBED 1024
#define HEADS 16
#define HD    64
#define NB    4
#define LSEQ  2048

typedef __attribute__((ext_vector_type(8))) short bf16x8;
typedef __attribute__((ext_vector_type(16))) float f32x16;

typedef __attribute__((address_space(1))) void as1_void;
typedef __attribute__((address_space(3))) void as3_void;

#if __has_builtin(__builtin_amdgcn_exp2f)
#define EXP2(x) __builtin_amdgcn_exp2f(x)
#else
#define EXP2(x) exp2f(x)
#endif

__device__ __forceinline__ void gload_lds16(const void* g, void* l) {
    __builtin_amdgcn_global_load_lds((const as1_void*)g, (as3_void*)l, 16, 0, 0);
}

__device__ inline bf16x8 as_bf16x8(uint4 u) {
    union { uint4 u; bf16x8 b; } c; c.u = u; return c.b;
}
// round-to-nearest-even fp32 -> bf16 (raw ushort); finite inputs only
__device__ inline unsigned short bf16r(float x) {
    unsigned u = __float_as_uint(x);
    u += 0x7fffu + ((u >> 16) & 1u);
    return (unsigned short)(u >> 16);
}
__device__ inline float bfh2f(unsigned short h) {
    return __uint_as_float(((unsigned)h) << 16);
}
// split two floats into packed hi/lo bf16 words
__device__ inline void split2(float x, float y, unsigned& hw, unsigned& lw) {
    unsigned short hx = bf16r(x), hy = bf16r(y);
    unsigned short lx = bf16r(x - bfh2f(hx)), ly = bf16r(y - bfh2f(hy));
    hw = (unsigned)hx | ((unsigned)hy << 16);
    lw = (unsigned)lx | ((unsigned)ly << 16);
}

// ---------------------------------------------------------------------------
// Kernel 1: QKV projections as split-bf16 MFMA GEMM (R12 form, unchanged).
// ---------------------------------------------------------------------------
__global__ __launch_bounds__(256, 3) void proj_kernel(
    const float* __restrict__ Xv, const float* __restrict__ Xk, const float* __restrict__ Xq,
    const float* __restrict__ Wv, const float* __restrict__ Wk, const float* __restrict__ Wq,
    const float* __restrict__ Wo,
    unsigned short* __restrict__ Vt, unsigned short* __restrict__ Kp, unsigned short* __restrict__ Qp,
    unsigned short* __restrict__ Woh, unsigned short* __restrict__ Wol)
{
    __shared__ uint4 sXh[128 * 8];   // [token][granule of 8 dims]  16KB
    __shared__ uint4 sXl[128 * 8];   // 16KB
    __shared__ uint4 sWh[64 * 8];    // [e][granule of 8 dims]       8KB
    __shared__ uint4 sWl[64 * 8];    //                              8KB

    const int t = threadIdx.x;

    // ---- z == 3: Wo hi/lo split (former wsplit_kernel) ----
    if (blockIdx.z == 3) {
        int w_id = blockIdx.x + blockIdx.y * 64;          // 0..1023
        int i = w_id * 256 + t;
        float4 v = ((const float4*)Wo)[i];
        ushort4 h4, l4;
        h4.x = bf16r(v.x); l4.x = bf16r(v.x - bfh2f(h4.x));
        h4.y = bf16r(v.y); l4.y = bf16r(v.y - bfh2f(h4.y));
        h4.z = bf16r(v.z); l4.z = bf16r(v.z - bfh2f(h4.z));
        h4.w = bf16r(v.w); l4.w = bf16r(v.w - bfh2f(h4.w));
        ((ushort4*)Woh)[i] = h4;
        ((ushort4*)Wol)[i] = l4;
        return;
    }

    const int lane = t & 63, w = t >> 6;
    const int l5 = lane & 31, hi = lane >> 5;
    const int h  = blockIdx.y;
    const int n  = blockIdx.x >> 4;
    const int l0 = (blockIdx.x & 15) * 128;
    const int p  = blockIdx.z;

    const float QSC = 1.44269504088896341f / 32.0f;
    const float* Xp = (p == 0) ? Xv : (p == 1) ? Xk : Xq;
    const float* Wp = (p == 0) ? Wv : (p == 1) ? Wk : Wq;

    const int frow = t >> 4;        // staging: row group 0..15
    const int fcol = t & 15;        // float4 index within 64-dim row

    // ---- stage X tile: 128 rows x 64 dims fp32 -> hi/lo bf16, swizzled ----
    {
        const float* xb = Xp + ((size_t)(n * LSEQ + l0 + frow)) * EMBED + h * HD + fcol * 4;
        unsigned short* dh = (unsigned short*)sXh;
        unsigned short* dl = (unsigned short*)sXl;
        #pragma unroll
        for (int i = 0; i < 8; ++i) {
            int row = frow + i * 16;
            float4 v = *(const float4*)(xb + (size_t)i * 16 * EMBED);
            int gg = fcol >> 1, s8 = (fcol & 1) * 4;
            int idx = row * 64 + ((gg ^ (row & 7)) * 8) + s8;
            uint2 hv, lv;
            split2(v.x, v.y, hv.x, lv.x);
            split2(v.z, v.w, hv.y, lv.y);
            *(uint2*)(dh + idx) = hv;
            *(uint2*)(dl + idx) = lv;
        }
    }
    // ---- stage W: 64x64 fp32 -> hi/lo bf16, swizzled ----
    #pragma unroll
    for (int i = 0; i < 2; ++i) {
        int u = t + 256 * i;                  // granule 0..511
        int e = u >> 3, g = u & 7;
        const float* wb = Wp + u * 8;
        float4 v0 = *(const float4*)(wb);
        float4 v1 = *(const float4*)(wb + 4);
        uint4 hq, lq;
        split2(v0.x, v0.y, hq.x, lq.x);
        split2(v0.z, v0.w, hq.y, lq.y);
        split2(v1.x, v1.y, hq.z, lq.z);
        split2(v1.z, v1.w, hq.w, lq.w);
        int idx = e * 8 + (g ^ (e & 7));
        sWh[idx] = hq;
        sWl[idx] = lq;
    }
    __syncthreads();

    // ---- MFMA: per wave, 32-token tile x (two 32-wide e-tiles) ----
    f32x16 acc0, acc1;
    #pragma unroll
    for (int i = 0; i < 16; ++i) { acc0[i] = 0.f; acc1[i] = 0.f; }

    const int xrow = w * 32 + l5;
    const int w0r = l5, w1r = 32 + l5;
    #pragma unroll
    for (int kc = 0; kc < 4; ++kc) {
        int gsel = kc * 2 + hi;
        bf16x8 xh = as_bf16x8(sXh[xrow * 8 + (gsel ^ (xrow & 7))]);
        bf16x8 xl = as_bf16x8(sXl[xrow * 8 + (gsel ^ (xrow & 7))]);
        bf16x8 wh0 = as_bf16x8(sWh[w0r * 8 + (gsel ^ (w0r & 7))]);
        bf16x8 wl0 = as_bf16x8(sWl[w0r * 8 + (gsel ^ (w0r & 7))]);
        bf16x8 wh1 = as_bf16x8(sWh[w1r * 8 + (gsel ^ (w1r & 7))]);
        bf16x8 wl1 = as_bf16x8(sWl[w1r * 8 + (gsel ^ (w1r & 7))]);
        if (p == 0) {
            // V^T = W X^T : A=W-frag (rows e), B=X-frag (cols token)
            acc0 = __builtin_amdgcn_mfma_f32_32x32x16_bf16(wh0, xh, acc0, 0, 0, 0);
            acc0 = __builtin_amdgcn_mfma_f32_32x32x16_bf16(wh0, xl, acc0, 0, 0, 0);
            acc0 = __builtin_amdgcn_mfma_f32_32x32x16_bf16(wl0, xh, acc0, 0, 0, 0);
            acc1 = __builtin_amdgcn_mfma_f32_32x32x16_bf16(wh1, xh, acc1, 0, 0, 0);
            acc1 = __builtin_amdgcn_mfma_f32_32x32x16_bf16(wh1, xl, acc1, 0, 0, 0);
            acc1 = __builtin_amdgcn_mfma_f32_32x32x16_bf16(wl1, xh, acc1, 0, 0, 0);
        } else {
            // C = X W^T : A=X-frag (rows token), B=W-frag (cols e)
            acc0 = __builtin_amdgcn_mfma_f32_32x32x16_bf16(xh, wh0, acc0, 0, 0, 0);
            acc0 = __builtin_amdgcn_mfma_f32_32x32x16_bf16(xh, wl0, acc0, 0, 0, 0);
            acc0 = __builtin_amdgcn_mfma_f32_32x32x16_bf16(xl, wh0, acc0, 0, 0, 0);
            acc1 = __builtin_amdgcn_mfma_f32_32x32x16_bf16(xh, wh1, acc1, 0, 0, 0);
            acc1 = __builtin_amdgcn_mfma_f32_32x32x16_bf16(xh, wl1, acc1, 0, 0, 0);
            acc1 = __builtin_amdgcn_mfma_f32_32x32x16_bf16(xl, wh1, acc1, 0, 0, 0);
        }
    }

    // ---- epilogue ----
    if (p == 0) {
        // C rows = e, cols = token (V^T): coalesced Vt [N,H,D,L] stores
        unsigned short* vb = Vt + (((size_t)(n * HEADS + h)) * HD) * LSEQ + l0 + w * 32 + l5;
        #pragma unroll
        for (int r = 0; r < 16; ++r) {
            int er = (r & 3) + 8 * (r >> 2) + 4 * hi;
            vb[(size_t)er * LSEQ]        = bf16r(acc0[r]);
            vb[(size_t)(32 + er) * LSEQ] = bf16r(acc1[r]);
        }
    } else {
        unsigned short* dst = (p == 1) ? Kp : Qp;
        float sc = (p == 2) ? QSC : 1.0f;
        unsigned short* db = dst + (((size_t)(n * HEADS + h)) * LSEQ + l0 + w * 32) * HD;
        #pragma unroll
        for (int r = 0; r < 16; ++r) {
            int tok = (r & 3) + 8 * (r >> 2) + 4 * hi;
            db[(size_t)tok * HD + l5]      = bf16r(acc0[r] * sc);
            db[(size_t)tok * HD + 32 + l5] = bf16r(acc1[r] * sc);
        }
    }
}

// ---------------------------------------------------------------------------
// Kernel 2: MFMA flash attention (R13 form, unchanged — dropped below the
// top-5 cutoff at <87us after zero-acc/unroll/T1).
// ---------------------------------------------------------------------------
__global__ __launch_bounds__(256, 4) void attn_kernel(
    const unsigned short* __restrict__ Qp, const unsigned short* __restrict__ Kp,
    const unsigned short* __restrict__ Vt,
    unsigned short* __restrict__ AOh, unsigned short* __restrict__ AOl)
{
    __shared__ uint4 sK[2][64 * 8];  // [buf][key][granule]  8KB each
    __shared__ uint4 sV[2][64 * 8];  // [buf][d][key-granule] 8KB each

    const int t = threadIdx.x;
    const int lane = t & 63, w = t >> 6;
    const int l5 = lane & 31, hi = lane >> 5;

    // T1 remap: b -> (xcd, u); group = xcd*8 + (u>>4) owns q-tiles u&15.
    const int b   = blockIdx.x + blockIdx.y * 16 + blockIdx.z * 256;
    const int xcd = b & 7, u = b >> 3;
    const int grp = xcd * 8 + (u >> 4);
    const int n   = grp >> 4, h = grp & 15;
    const int q0  = (u & 15) * 128;

    const size_t hoff = ((size_t)n * HEADS + h) * (size_t)(LSEQ * HD);
    const unsigned short* Kh = Kp + hoff;
    const unsigned short* Vh = Vt + hoff;

    bf16x8 qf[4];
    {
        const uint4* qg = (const uint4*)(Qp + hoff + (size_t)(q0 + w * 32 + l5) * HD);
        #pragma unroll
        for (int kc = 0; kc < 4; ++kc) qf[kc] = as_bf16x8(qg[kc * 2 + hi]);
    }

    f32x16 z16;
    #pragma unroll
    for (int i = 0; i < 16; ++i) z16[i] = 0.f;
    f32x16 Oa0 = z16, Oa1 = z16;
    float ls0 = 0.f, ls1 = 0.f;

    const int r0 = t >> 3;                       // key-row / d-row 0..31
    const int g0 = (t & 7) ^ (r0 & 7);           // swizzled granule
    const uint4* gK = (const uint4*)Kh;
    const uint4* gV = (const uint4*)Vh;          // V^T: 256 uint4 per d-row

    #define STAGE(TILE, BUF)                                                        \
        do {                                                                        \
            int kb_ = (TILE) * 64;                                                  \
            gload_lds16(gK + (size_t)(kb_ + r0) * 8 + g0,        &sK[BUF][t]);      \
            gload_lds16(gK + (size_t)(kb_ + r0 + 32) * 8 + g0,   &sK[BUF][t + 256]);\
            gload_lds16(gV + (size_t)r0 * 256 + (kb_ >> 3) + g0, &sV[BUF][t]);      \
            gload_lds16(gV + (size_t)(r0 + 32) * 256 + (kb_ >> 3) + g0,             \
                        &sV[BUF][t + 256]);                                         \
        } while (0)

    #define COMPUTE(BUF)                                                            \
        do {                                                                        \
            _Pragma("unroll")                                                       \
            for (int tc = 0; tc < 2; ++tc) {                                        \
                int key = tc * 32 + l5;                                             \
                __builtin_amdgcn_s_setprio(1);                                      \
                bf16x8 kf0 = as_bf16x8(sK[BUF][key * 8 + (hi ^ (l5 & 7))]);         \
                f32x16 c = __builtin_amdgcn_mfma_f32_32x32x16_bf16(kf0, qf[0], z16, 0, 0, 0); \
                _Pragma("unroll")                                                   \
                for (int kc = 1; kc < 4; ++kc) {                                    \
                    bf16x8 kf = as_bf16x8(sK[BUF][key * 8 + ((kc * 2 + hi) ^ (l5 & 7))]); \
                    c = __builtin_amdgcn_mfma_f32_32x32x16_bf16(kf, qf[kc], c, 0, 0, 0);  \
                }                                                                   \
                __builtin_amdgcn_s_setprio(0);                                      \
                uint4 pwa, pwb;                                                     \
                {                                                                   \
                    float p0 = EXP2(c[0]),  p1 = EXP2(c[1]);                        \
                    float p2 = EXP2(c[2]),  p3 = EXP2(c[3]);                        \
                    ls0 += p0 + p1; ls1 += p2 + p3;                                 \
                    asm("v_cvt_pk_bf16_f32 %0, %1, %2" : "=v"(pwa.x) : "v"(p0), "v"(p1)); \
                    asm("v_cvt_pk_bf16_f32 %0, %1, %2" : "=v"(pwa.y) : "v"(p2), "v"(p3)); \
                    p0 = EXP2(c[4]);  p1 = EXP2(c[5]);                              \
                    p2 = EXP2(c[6]);  p3 = EXP2(c[7]);                              \
                    ls0 += p0 + p1; ls1 += p2 + p3;                                 \
                    asm("v_cvt_pk_bf16_f32 %0, %1, %2" : "=v"(pwa.z) : "v"(p0), "v"(p1)); \
                    asm("v_cvt_pk_bf16_f32 %0, %1, %2" : "=v"(pwa.w) : "v"(p2), "v"(p3)); \
                    p0 = EXP2(c[8]);  p1 = EXP2(c[9]);                              \
                    p2 = EXP2(c[10]); p3 = EXP2(c[11]);                             \
                    ls0 += p0 + p1; ls1 += p2 + p3;                                 \
                    asm("v_cvt_pk_bf16_f32 %0, %1, %2" : "=v"(pwb.x) : "v"(p0), "v"(p1)); \
                    asm("v_cvt_pk_bf16_f32 %0, %1, %2" : "=v"(pwb.y) : "v"(p2), "v"(p3)); \
                    p0 = EXP2(c[12]); p1 = EXP2(c[13]);                             \
                    p2 = EXP2(c[14]); p3 = EXP2(c[15]);                             \
                    ls0 += p0 + p1; ls1 += p2 + p3;                                 \
                    asm("v_cvt_pk_bf16_f32 %0, %1, %2" : "=v"(pwb.z) : "v"(p0), "v"(p1)); \
                    asm("v_cvt_pk_bf16_f32 %0, %1, %2" : "=v"(pwb.w) : "v"(p2), "v"(p3)); \
                }                                                                   \
                asm("v_permlane32_swap_b32 %0, %1" : "+v"(pwa.x), "+v"(pwa.z));     \
                asm("v_permlane32_swap_b32 %0, %1" : "+v"(pwa.y), "+v"(pwa.w));     \
                asm("v_permlane32_swap_b32 %0, %1" : "+v"(pwb.x), "+v"(pwb.z));     \
                asm("v_permlane32_swap_b32 %0, %1" : "+v"(pwb.y), "+v"(pwb.w));     \
                __builtin_amdgcn_s_setprio(1);                                      \
                {                                                                   \
                    int vg0 = tc * 4 + hi;                                          \
                    bf16x8 pa = as_bf16x8(pwa);                                     \
                    bf16x8 v0 = as_bf16x8(sV[BUF][ l5       * 8 + (vg0 ^ (l5 & 7))]); \
                    Oa0 = __builtin_amdgcn_mfma_f32_32x32x16_bf16(pa, v0, Oa0, 0, 0, 0); \
                    bf16x8 v1 = as_bf16x8(sV[BUF][(32 + l5) * 8 + (vg0 ^ (l5 & 7))]); \
                    Oa1 = __builtin_amdgcn_mfma_f32_32x32x16_bf16(pa, v1, Oa1, 0, 0, 0); \
                    int vg1 = tc * 4 + 2 + hi;                                      \
                    bf16x8 pb = as_bf16x8(pwb);                                     \
                    bf16x8 v2 = as_bf16x8(sV[BUF][ l5       * 8 + (vg1 ^ (l5 & 7))]); \
                    Oa0 = __builtin_amdgcn_mfma_f32_32x32x16_bf16(pb, v2, Oa0, 0, 0, 0); \
                    bf16x8 v3 = as_bf16x8(sV[BUF][(32 + l5) * 8 + (vg1 ^ (l5 & 7))]); \
                    Oa1 = __builtin_amdgcn_mfma_f32_32x32x16_bf16(pb, v3, Oa1, 0, 0, 0); \
                }                                                                   \
                __builtin_amdgcn_s_setprio(0);                                      \
            }                                                                       \
        } while (0)

    STAGE(0, 0);

    for (int tt = 0; tt < LSEQ / 64; tt += 2) {
        STAGE(tt + 1, 1);
        asm volatile("s_waitcnt vmcnt(4)" ::: "memory");
        __builtin_amdgcn_s_barrier();
        COMPUTE(0);
        __builtin_amdgcn_s_barrier();

        if (tt + 2 < LSEQ / 64) {
            STAGE(tt + 2, 0);
            asm volatile("s_waitcnt vmcnt(4)" ::: "memory");
        } else {
            asm volatile("s_waitcnt vmcnt(0)" ::: "memory");
        }
        __builtin_amdgcn_s_barrier();
        COMPUTE(1);
        __builtin_amdgcn_s_barrier();
    }
    #undef STAGE
    #undef COMPUTE

    float lsum = ls0 + ls1;
    lsum += __shfl_xor(lsum, 32);
    float inv = 1.0f / lsum;
    float* sLf = (float*)&sK[0][0];
    if (hi == 0) sLf[w * 32 + l5] = inv;
    __syncthreads();

    unsigned short* hB = AOh + hoff;
    unsigned short* lB = AOl + hoff;
    #pragma unroll
    for (int r = 0; r < 16; ++r) {
        int qr = (r & 3) + 8 * (r >> 2) + 4 * hi;
        float invq = sLf[w * 32 + qr];
        size_t row = (size_t)(q0 + w * 32 + qr) * HD;
        float o0 = Oa0[r] * invq;
        float o1 = Oa1[r] * invq;
        unsigned short h0 = bf16r(o0), h1 = bf16r(o1);
        hB[row +      l5] = h0;
        hB[row + 32 + l5] = h1;
        lB[row +      l5] = bf16r(o0 - bfh2f(h0));
        lB[row + 32 + l5] = bf16r(o1 - bfh2f(h1));
    }
}

// ---------------------------------------------------------------------------
// Kernel 3: output projection, split-bf16 MFMA GEMM.
// R14: kill the 1.887e7 LDS bank conflicts (~31us/CU-equivalent, 35% of the
// 88us kernel; VALUBusy 12.7% so there is nothing to hide them behind).
// Root cause: 64B-stride rows + 2-bit XOR -> half-wave hits only 4 of 8
// bank-start groups (8-way serialize).  Fix: merge hi/lo into 128B-stride
// tiles (sA[128][8], sB[64][8]; granules 0-3 = hi, 4-7 = lo) with the deep
// swizzle SW(r)=(r^(r>>3))&7 — the exact pattern that measurably zeroed
// attn's conflicts in R9.  In outproj all read rows are THREAD-FIXED, so
// the swizzle constants are loop-invariant: zero inner-loop VALU cost
// (unlike attn, where R9 regressed).  Source-side applies the same
// involution (both-sides-or-neither); per-lane hi/lo pointer select is
// legal (global source of global_load_lds is per-lane).  LDS total still
// 48KB -> 3 blocks/CU; 6 loads/chunk -> vmcnt(6) unchanged.
// ---------------------------------------------------------------------------
__global__ __launch_bounds__(256, 3) void outproj_kernel(
    const unsigned short* __restrict__ AOh, const unsigned short* __restrict__ AOl,
    const unsigned short* __restrict__ Woh, const unsigned short* __restrict__ Wol,
    const float* __restrict__ bo, float* __restrict__ out)
{
    __shared__ uint4 sA[2][1024];   // [buf][token row 0..127][8 granules] 16KB each
    __shared__ uint4 sB[2][512];    // [buf][e row 0..63][8 granules]       8KB each

    const int t = threadIdx.x;
    const int lane = t & 63, w = t >> 6;
    const int l5 = lane & 31, hi = lane >> 5;

    // T1 remap: l -> (xcd, u); m-tile = xcd*8 + (u&7), e-tile = u>>3.
    const int bl  = blockIdx.x + blockIdx.y * 64;
    const int xcd = bl & 7, u = bl >> 3;
    const int m0  = (xcd * 8 + (u & 7)) * 128;
    const int e0  = (u >> 3) * 64;
    const int n   = m0 >> 11, l0 = m0 & 2047;

    #define SW(r) (((r) ^ ((r) >> 3)) & 7)

    #define OSTAGE(C, BUF)                                                            \
        do {                                                                          \
            int hh_ = (C) >> 1, hf_ = (C) & 1;                                        \
            const uint4* gAh_ = (const uint4*)(AOh) +                                 \
                (((size_t)n * HEADS + hh_) * LSEQ + l0) * 8 + hf_ * 4;                \
            const uint4* gAl_ = (const uint4*)(AOl) +                                 \
                (((size_t)n * HEADS + hh_) * LSEQ + l0) * 8 + hf_ * 4;                \
            const uint4* gBh_ = (const uint4*)(Woh) +                                 \
                (size_t)e0 * 128 + hh_ * 8 + hf_ * 4;                                 \
            const uint4* gBl_ = (const uint4*)(Wol) +                                 \
                (size_t)e0 * 128 + hh_ * 8 + hf_ * 4;                                 \
            _Pragma("unroll")                                                         \
            for (int i_ = 0; i_ < 4; ++i_) {                                          \
                int s_ = t + 256 * i_;                                                \
                int row_ = s_ >> 3, sg_ = (s_ & 7) ^ SW(row_);                        \
                const uint4* src_ = (sg_ < 4 ? gAh_ : gAl_) +                         \
                    (size_t)row_ * 8 + (sg_ & 3);                                     \
                gload_lds16(src_, &sA[BUF][s_]);                                      \
            }                                                                         \
            _Pragma("unroll")                                                         \
            for (int i_ = 0; i_ < 2; ++i_) {                                          \
                int s_ = t + 256 * i_;                                                \
                int row_ = s_ >> 3, sg_ = (s_ & 7) ^ SW(row_);                        \
                const uint4* src_ = (sg_ < 4 ? gBh_ : gBl_) +                         \
                    (size_t)row_ * 128 + (sg_ & 3);                                   \
                gload_lds16(src_, &sB[BUF][s_]);                                      \
            }                                                                         \
        } while (0)

    f32x16 acc0, acc1;
    #pragma unroll
    for (int i = 0; i < 16; ++i) { acc0[i] = 0.f; acc1[i] = 0.f; }

    OSTAGE(0, 0);
    int cur = 0;

    const int amr = w * 32 + l5;                 // A fragment row (token), fixed
    const int swa  = SW(amr);                    // thread-invariant swizzles
    const int swb0 = SW(l5);
    const int swb1 = SW(32 + l5);

    for (int c = 0; c < 32; ++c) {
        if (c + 1 < 32) {
            OSTAGE(c + 1, cur ^ 1);
            asm volatile("s_waitcnt vmcnt(6)" ::: "memory");
        } else {
            asm volatile("s_waitcnt vmcnt(0)" ::: "memory");
        }
        __builtin_amdgcn_s_barrier();

        __builtin_amdgcn_s_setprio(1);
        #pragma unroll
        for (int ks = 0; ks < 2; ++ks) {
            int gx = ks * 2 + hi;
            bf16x8 ah  = as_bf16x8(sA[cur][amr * 8       + ( gx      ^ swa )]);
            bf16x8 al  = as_bf16x8(sA[cur][amr * 8       + ((gx + 4) ^ swa )]);
            bf16x8 bh0 = as_bf16x8(sB[cur][ l5       * 8 + ( gx      ^ swb0)]);
            bf16x8 bh1 = as_bf16x8(sB[cur][(32 + l5) * 8 + ( gx      ^ swb1)]);
            bf16x8 bl0 = as_bf16x8(sB[cur][ l5       * 8 + ((gx + 4) ^ swb0)]);
            bf16x8 bl1 = as_bf16x8(sB[cur][(32 + l5) * 8 + ((gx + 4) ^ swb1)]);

            acc0 = __builtin_amdgcn_mfma_f32_32x32x16_bf16(ah, bh0, acc0, 0, 0, 0);
            acc1 = __builtin_amdgcn_mfma_f32_32x32x16_bf16(ah, bh1, acc1, 0, 0, 0);
            acc0 = __builtin_amdgcn_mfma_f32_32x32x16_bf16(ah, bl0, acc0, 0, 0, 0);
            acc1 = __builtin_amdgcn_mfma_f32_32x32x16_bf16(ah, bl1, acc1, 0, 0, 0);
            acc0 = __builtin_amdgcn_mfma_f32_32x32x16_bf16(al, bh0, acc0, 0, 0, 0);
            acc1 = __builtin_amdgcn_mfma_f32_32x32x16_bf16(al, bh1, acc1, 0, 0, 0);
        }
        __builtin_amdgcn_s_setprio(0);
        __builtin_amdgcn_s_barrier();
        cur ^= 1;
    }
    #undef OSTAGE
    #undef SW

    float b0 = bo[e0 + l5];
    float b1 = bo[e0 + 32 + l5];
    #pragma unroll
    for (int r = 0; r < 16; ++r) {
        int row = m0 + w * 32 + (r & 3) + 8 * (r >> 2) + 4 * hi;
        float* o = out + (size_t)row * EMBED + e0;
        o[l5]      = acc0[r] + b0;
        o[32 + l5] = acc1[r] + b1;
    }
}

// ---------------------------------------------------------------------------
extern "C" void kernel_launch(void* const* d_in, const int* in_sizes, int n_in,
                              void* d_out, int out_size, void* d_ws, size_t ws_size,
                              hipStream_t stream)
{
    const float* values  = (const float*)d_in[0];
    const float* keys    = (const float*)d_in[1];
    const float* queries = (const float*)d_in[2];
    const float* Wv      = (const float*)d_in[3];
    const float* Wk      = (const float*)d_in[4];
    const float* Wq      = (const float*)d_in[5];
    const float* Wo      = (const float*)d_in[6];
    const float* bo      = (const float*)d_in[7];
    float* out = (float*)d_out;

    const size_t bufElems = (size_t)NB * HEADS * LSEQ * HD;   // 8,388,608
    unsigned short* Qp  = (unsigned short*)d_ws;
    unsigned short* Kp  = Qp  + bufElems;
    unsigned short* Vt  = Kp  + bufElems;
    unsigned short* AOh = Vt  + bufElems;
    unsigned short* AOl = AOh + bufElems;
    unsigned short* Woh = AOl + bufElems;
    unsigned short* Wol = Woh + (size_t)EMBED * EMBED;

    proj_kernel<<<dim3(NB * 16, HEADS, 4), 256, 0, stream>>>(
        values, keys, queries, Wv, Wk, Wq, Wo, Vt, Kp, Qp, Woh, Wol);
    attn_kernel<<<dim3(LSEQ / 128, HEADS, NB), 256, 0, stream>>>(Qp, Kp, Vt, AOh, AOl);
    outproj_kernel<<<dim3(NB * LSEQ / 128, EMBED / 64), 256, 0, stream>>>(AOh, AOl, Woh, Wol, bo, out);
}